// Round 1
// 3695.940 us; speedup vs baseline: 1.1892x; 1.1892x over previous
//
#include <hip/hip_runtime.h>

// Problem constants
#define HW     16384      // 128*128
#define NB     8
#define CDIM   192
#define CH3    576
#define NHEADS 4
#define CHH    48
#define TROWS  16           // FFN tile rows
#define TSLOT  18           // + halo
#define NT     (TSLOT*128)  // 2304
#define NF     (TROWS*128)  // 2048
#define NGRP   4            // batches per FFN group
#define LDA    40           // LDS k-stride (bf16 elems): 80B, 16B-mult, 2-way-free banks
#define NSL    64           // gram1 n-slices (grid = NSL x 4 heads = 256 blocks)

typedef short  v8s  __attribute__((ext_vector_type(8)));
typedef float  v4f  __attribute__((ext_vector_type(4)));
typedef unsigned short u16x8 __attribute__((ext_vector_type(8)));

__device__ __forceinline__ float bf2f(unsigned short s) {
    return __uint_as_float(((unsigned)s) << 16);
}
__device__ __forceinline__ unsigned short f2bf(float f) {
    unsigned u = __float_as_uint(f);
    return (unsigned short)((u + 0x7fffu + ((u >> 16) & 1u)) >> 16);
}
__device__ __forceinline__ float gelu_f(float x) {
    return 0.5f * x * (1.0f + erff(x * 0.70710678118654752f));
}

// ---------------------------------------------------------------------------
// LayerNorm stats per pixel over 192 channels. grid (64, Z)
// ---------------------------------------------------------------------------
__global__ __launch_bounds__(256) void ln_stats(const float* __restrict__ x,
                                                float* __restrict__ mu,
                                                float* __restrict__ rstd) {
    int p = blockIdx.x * 256 + threadIdx.x;
    int z = blockIdx.y;
    const float* xp = x + (size_t)z * CDIM * HW;
    float s = 0.f, ss = 0.f;
    for (int c = 0; c < CDIM; ++c) {
        float v = xp[(size_t)c * HW + p];
        s += v; ss += v * v;
    }
    float m = s * (1.0f / CDIM);
    float var = ss * (1.0f / CDIM) - m * m;
    mu[z * HW + p] = m;
    rstd[z * HW + p] = 1.0f / sqrtf(var + 1e-5f);
}

// ---------------------------------------------------------------------------
// MFMA bf16 GEMM: out[m,n] = sum_k W[m,k] * X[k,n]  (fp32 acc/epilogue)
// Block: 256 thr = 4 waves (2x2), tile M=64 x N=128, K-step 32.
// B_MODE 0: X = layernorm(fp32 Bin) cast bf16 at stage; 1: bf16 buffer.
// EPI 0: +bias -> bf16; 1: +bias,gelu -> bf16; 2: +bias,+res(fp32) -> fp32.
// grid (N/128, M/64, Z)
// ---------------------------------------------------------------------------
template <int B_MODE, int EPI>
__global__ __launch_bounds__(256) void gemm_mfma(
    const float* __restrict__ Aw,
    const void* __restrict__ Bin, int b_cs, long b_zs,
    const float* __restrict__ mu, const float* __restrict__ rstd,
    const float* __restrict__ lnw, const float* __restrict__ lnb,
    const float* __restrict__ bias,
    const float* __restrict__ res, int r_cs, long r_zs,
    void* __restrict__ outp, int o_cs, long o_zs,
    int M, int K) {
    __shared__ unsigned short Albs[64 * LDA];
    __shared__ unsigned short Blbs[128 * LDA];

    const int t  = threadIdx.x;
    const int n0 = blockIdx.x * 128;
    const int m0 = blockIdx.y * 64;
    const int z  = blockIdx.z;

    const int wid = t >> 6, lane = t & 63;
    const int lm = lane & 15, quad = lane >> 4;
    const int wm = (wid & 1) * 32, wn = (wid >> 1) * 64;

    v4f acc[2][4];
#pragma unroll
    for (int mi = 0; mi < 2; ++mi)
#pragma unroll
        for (int ni = 0; ni < 4; ++ni) acc[mi][ni] = (v4f)0.0f;

    // staging coords
    const int am = t >> 2, kc = (t & 3) << 3;       // A: 64 m x 4 k-chunks of 8
    const int bk = t >> 3, nc = (t & 7) << 4;       // B: 32 k x 8 n-chunks of 16

    for (int k0 = 0; k0 < K; k0 += 32) {
        if (k0) __syncthreads();
        // --- stage A (64 x 32), fp32 -> bf16, layout [m][k] ---
        {
            const float* wp = Aw + (size_t)(m0 + am) * K + k0 + kc;
            float4 w0 = *(const float4*)wp;
            float4 w1 = *(const float4*)(wp + 4);
            u16x8 u;
            u[0] = f2bf(w0.x); u[1] = f2bf(w0.y); u[2] = f2bf(w0.z); u[3] = f2bf(w0.w);
            u[4] = f2bf(w1.x); u[5] = f2bf(w1.y); u[6] = f2bf(w1.z); u[7] = f2bf(w1.w);
            *(u16x8*)&Albs[am * LDA + kc] = u;
        }
        // --- stage B (32 k x 128 n) transposed to [n][k] ---
        if (B_MODE == 1) {
            const unsigned short* bp = (const unsigned short*)Bin + (size_t)z * b_zs +
                                       (size_t)(k0 + bk) * b_cs + n0 + nc;
            u16x8 u0 = *(const u16x8*)bp;
            u16x8 u1 = *(const u16x8*)(bp + 8);
#pragma unroll
            for (int i = 0; i < 8; ++i) {
                Blbs[(nc + i) * LDA + bk]     = u0[i];
                Blbs[(nc + 8 + i) * LDA + bk] = u1[i];
            }
        } else {
            const float* xp = (const float*)Bin + (size_t)z * b_zs +
                              (size_t)(k0 + bk) * b_cs + n0 + nc;
            const float* mp = mu + n0 + nc;
            const float* rp = rstd + n0 + nc;
            float lw = lnw[k0 + bk], lb = lnb[k0 + bk];
#pragma unroll
            for (int q = 0; q < 4; ++q) {
                float4 xv = *(const float4*)(xp + 4 * q);
                float4 mv = *(const float4*)(mp + 4 * q);
                float4 rv = *(const float4*)(rp + 4 * q);
                Blbs[(nc + 4 * q + 0) * LDA + bk] = f2bf((xv.x - mv.x) * rv.x * lw + lb);
                Blbs[(nc + 4 * q + 1) * LDA + bk] = f2bf((xv.y - mv.y) * rv.y * lw + lb);
                Blbs[(nc + 4 * q + 2) * LDA + bk] = f2bf((xv.z - mv.z) * rv.z * lw + lb);
                Blbs[(nc + 4 * q + 3) * LDA + bk] = f2bf((xv.w - mv.w) * rv.w * lw + lb);
            }
        }
        __syncthreads();
        // --- 2x4 MFMA 16x16x32 ---
        v8s a[2], b[4];
#pragma unroll
        for (int mi = 0; mi < 2; ++mi)
            a[mi] = *(const v8s*)&Albs[(wm + mi * 16 + lm) * LDA + quad * 8];
#pragma unroll
        for (int ni = 0; ni < 4; ++ni)
            b[ni] = *(const v8s*)&Blbs[(wn + ni * 16 + lm) * LDA + quad * 8];
#pragma unroll
        for (int mi = 0; mi < 2; ++mi)
#pragma unroll
            for (int ni = 0; ni < 4; ++ni)
                acc[mi][ni] = __builtin_amdgcn_mfma_f32_16x16x32_bf16(
                    a[mi], b[ni], acc[mi][ni], 0, 0, 0);
    }

    // --- epilogue: D row = quad*4+r, col = lm ---
#pragma unroll
    for (int mi = 0; mi < 2; ++mi)
#pragma unroll
        for (int ni = 0; ni < 4; ++ni)
#pragma unroll
            for (int r = 0; r < 4; ++r) {
                int gm = m0 + wm + mi * 16 + quad * 4 + r;
                int gn = n0 + wn + ni * 16 + lm;
                float v = acc[mi][ni][r] + bias[gm];
                if (EPI == 1) v = gelu_f(v);
                if (EPI == 2) {
                    size_t ri = (size_t)z * r_zs + (size_t)gm * r_cs + gn;
                    size_t oi = (size_t)z * o_zs + (size_t)gm * o_cs + gn;
                    ((float*)outp)[oi] = v + res[ri];
                } else {
                    size_t oi = (size_t)z * o_zs + (size_t)gm * o_cs + gn;
                    ((unsigned short*)outp)[oi] = f2bf(v);
                }
            }
}

// ---------------------------------------------------------------------------
// Depthwise 3x3 (pad=1) + bias + prompt[c%192] on 576-ch bf16. grid (64, 576)
// ---------------------------------------------------------------------------
__global__ __launch_bounds__(256) void dwp(const unsigned short* __restrict__ in,
                                           const float* __restrict__ w9,
                                           const float* __restrict__ b1,
                                           const float* __restrict__ prompt,
                                           unsigned short* __restrict__ out) {
    int p = blockIdx.x * 256 + threadIdx.x;
    int c = blockIdx.y;
    int h = p >> 7, w = p & 127;
    const unsigned short* ip = in + (size_t)c * HW;
    const float* wp = w9 + c * 9;
    float acc = b1[c] + prompt[c % CDIM];
#pragma unroll
    for (int ky = 0; ky < 3; ++ky) {
        int hy = h + ky - 1;
        if ((unsigned)hy < 128u) {
            int rb = hy << 7;
#pragma unroll
            for (int kx = 0; kx < 3; ++kx) {
                int wx = w + kx - 1;
                if ((unsigned)wx < 128u)
                    acc += wp[ky * 3 + kx] * bf2f(ip[rb + wx]);
            }
        }
    }
    out[(size_t)c * HW + p] = f2bf(acc);
}

// ---------------------------------------------------------------------------
// 1/max(L2norm,1e-12) per q,k channel (0..383). grid 384
// ---------------------------------------------------------------------------
__global__ __launch_bounds__(256) void inv_norms1(const unsigned short* __restrict__ qk,
                                                  float* __restrict__ invn) {
    int ch = blockIdx.x;
    const unsigned short* p = qk + (size_t)ch * HW;
    float ss = 0.f;
    for (int i = threadIdx.x; i < HW; i += 256) { float v = bf2f(p[i]); ss += v * v; }
    __shared__ float r[256];
    r[threadIdx.x] = ss;
    __syncthreads();
    for (int off = 128; off; off >>= 1) {
        if (threadIdx.x < (unsigned)off) r[threadIdx.x] += r[threadIdx.x + off];
        __syncthreads();
    }
    if (threadIdx.x == 0) invn[ch] = 1.0f / fmaxf(sqrtf(r[0]), 1e-12f);
}

// ---------------------------------------------------------------------------
// Gram partials via MFMA: G0p[(h*NSL + sl)][qc*48+kc].
// grid (NSL, 4 heads) = 256 blocks, 256 thr = 4 waves.
// Each wave: full 48x48 (3x3 tiles of 16x16x32 bf16) over its 64-col n-range,
// A/B fragments loaded directly from global (rows contiguous in n).
// ---------------------------------------------------------------------------
__global__ __launch_bounds__(256) void gram1(const unsigned short* __restrict__ qk,
                                             float* __restrict__ G0p) {
    const int sl = blockIdx.x, h = blockIdx.y;
    const int t = threadIdx.x;
    const int wid = t >> 6, lane = t & 63;
    const int lm = lane & 15, quad = lane >> 4;

    const unsigned short* qb = qk + (size_t)(h * CHH) * HW;
    const unsigned short* kb = qk + (size_t)(192 + h * CHH) * HW;

    v4f acc[3][3];
#pragma unroll
    for (int mi = 0; mi < 3; ++mi)
#pragma unroll
        for (int ni = 0; ni < 3; ++ni) acc[mi][ni] = (v4f)0.0f;

    // wave covers n in [sl*256 + wid*64, +64): two K-steps of 32
    const int nbase = sl * 256 + wid * 64 + quad * 8;
#pragma unroll
    for (int ks = 0; ks < 2; ++ks) {
        const int n = nbase + ks * 32;
        v8s a[3], b[3];
#pragma unroll
        for (int i = 0; i < 3; ++i) {
            a[i] = *(const v8s*)(qb + (size_t)(i * 16 + lm) * HW + n);
            b[i] = *(const v8s*)(kb + (size_t)(i * 16 + lm) * HW + n);
        }
#pragma unroll
        for (int mi = 0; mi < 3; ++mi)
#pragma unroll
            for (int ni = 0; ni < 3; ++ni)
                acc[mi][ni] = __builtin_amdgcn_mfma_f32_16x16x32_bf16(
                    a[mi], b[ni], acc[mi][ni], 0, 0, 0);
    }

    // cross-wave reduce in LDS, one fp32 partial per block
    __shared__ float Gs[4][2304];
#pragma unroll
    for (int mi = 0; mi < 3; ++mi)
#pragma unroll
        for (int ni = 0; ni < 3; ++ni)
#pragma unroll
            for (int r = 0; r < 4; ++r)
                Gs[wid][(mi * 16 + quad * 4 + r) * 48 + ni * 16 + lm] = acc[mi][ni][r];
    __syncthreads();
    float* gp = G0p + ((size_t)h * NSL + sl) * 2304;
    for (int i = t; i < 2304; i += 256)
        gp[i] = Gs[0][i] + Gs[1][i] + Gs[2][i] + Gs[3][i];
}

// ---------------------------------------------------------------------------
// logits = T*G*invq*invk; softmax over d. grid 4 x 256 thr, NSL partials
// ---------------------------------------------------------------------------
__global__ __launch_bounds__(256) void softmax1(const float* __restrict__ G0p,
                                                const float* __restrict__ invn,
                                                const float* __restrict__ temp,
                                                float* __restrict__ Amat) {
    int h = blockIdx.x;
    int t = threadIdx.x;
    __shared__ float Gs[2304];
    const float* gbase = G0p + (size_t)h * NSL * 2304;
    for (int i = t; i < 2304; i += 256) {
        float s = 0.f;
#pragma unroll 8
        for (int sl = 0; sl < NSL; ++sl) s += gbase[(size_t)sl * 2304 + i];
        Gs[i] = s;
    }
    __syncthreads();
    if (t < 48) {
        float T = temp[h];
        float invq = invn[h * CHH + t];
        const float* gr = &Gs[t * 48];
        float lg[48];
        float mx = -1e30f;
#pragma unroll
        for (int d = 0; d < 48; ++d) {
            float l = T * gr[d] * invq * invn[192 + h * CHH + d];
            lg[d] = l;
            mx = fmaxf(mx, l);
        }
        float sum = 0.f;
#pragma unroll
        for (int d = 0; d < 48; ++d) { float e = expf(lg[d] - mx); lg[d] = e; sum += e; }
        float inv = 1.0f / sum;
        float* ap = Amat + (size_t)h * 2304 + t * 48;
#pragma unroll
        for (int d = 0; d < 48; ++d) ap[d] = lg[d] * inv;
    }
}

// ---------------------------------------------------------------------------
// attnout[c,n] = sum_d A[c,d]*v~[d,n] per head (bf16 in/out). grid (64, 4)
// ---------------------------------------------------------------------------
__global__ __launch_bounds__(256) void apply1(const unsigned short* __restrict__ qkvT,
                                              const float* __restrict__ Amat,
                                              unsigned short* __restrict__ attnout) {
    int n = blockIdx.x * 256 + threadIdx.x;
    int h = blockIdx.y;
    __shared__ float As[2304];
    for (int i = threadIdx.x; i < 2304; i += 256) As[i] = Amat[(size_t)h * 2304 + i];
    __syncthreads();
    const unsigned short* vp = qkvT + (size_t)(384 + h * CHH) * HW + n;
    float acc[48];
#pragma unroll
    for (int c = 0; c < 48; ++c) acc[c] = 0.f;
    for (int d = 0; d < 48; ++d) {
        float v = bf2f(vp[(size_t)d * HW]);
#pragma unroll
        for (int c = 0; c < 48; ++c) acc[c] = fmaf(As[c * 48 + d], v, acc[c]);
    }
    unsigned short* op = attnout + (size_t)(h * CHH) * HW + n;
#pragma unroll
    for (int c = 0; c < 48; ++c) op[(size_t)c * HW] = f2bf(acc[c]);
}

// ---------------------------------------------------------------------------
// FFN grouped 3x3 (192->576) + LN fused, row-tile +halo, z-batched.
// grid (NT/256, 576, NGRP). Junk (finite) for invalid global rows.
// ---------------------------------------------------------------------------
__global__ __launch_bounds__(256) void dwln_tile(const float* __restrict__ x2,
                                                 const float* __restrict__ mu,
                                                 const float* __restrict__ rstd,
                                                 const float* __restrict__ lnw,
                                                 const float* __restrict__ lnb,
                                                 const float* __restrict__ w9,
                                                 const float* __restrict__ b1,
                                                 unsigned short* __restrict__ f1, int r0) {
    int p = blockIdx.x * 256 + threadIdx.x;   // 0..NT-1
    int c = blockIdx.y, z = blockIdx.z;
    int s = p >> 7, w = p & 127;
    int gr = r0 - 1 + s;
    int g = c / 3;
    const float* ip = x2 + (size_t)z * CDIM * HW + (size_t)g * HW;
    const float* mp = mu + (size_t)z * HW;
    const float* rp = rstd + (size_t)z * HW;
    float lw = lnw[g], lb = lnb[g];
    const float* wp = w9 + c * 9;
    float acc = b1[c];
#pragma unroll
    for (int ky = 0; ky < 3; ++ky) {
        int hy = gr + ky - 1;
        if ((unsigned)hy < 128u) {
            int rb = hy << 7;
#pragma unroll
            for (int kx = 0; kx < 3; ++kx) {
                int wx = w + kx - 1;
                if ((unsigned)wx < 128u) {
                    int idx = rb + wx;
                    float v = (ip[idx] - mp[idx]) * rp[idx] * lw + lb;
                    acc += wp[ky * 3 + kx] * v;
                }
            }
        }
    }
    f1[(size_t)z * CH3 * NT + (size_t)c * NT + p] = f2bf(acc);
}

// ---------------------------------------------------------------------------
// FFN depthwise 3x3 on f2 tile -> f3, z-batched. grid (NF/256, 576, NGRP)
// ---------------------------------------------------------------------------
__global__ __launch_bounds__(256) void dw2_tile(const unsigned short* __restrict__ f2,
                                                const float* __restrict__ w9,
                                                const float* __restrict__ b1,
                                                unsigned short* __restrict__ f3, int r0) {
    int p = blockIdx.x * 256 + threadIdx.x;   // 0..NF-1
    int c = blockIdx.y, z = blockIdx.z;
    int rr = p >> 7, w = p & 127;
    const unsigned short* ip = f2 + (size_t)z * CH3 * NT + (size_t)c * NT;
    const float* wp = w9 + c * 9;
    float acc = b1[c];
#pragma unroll
    for (int ky = 0; ky < 3; ++ky) {
        int gy = r0 + rr + ky - 1;
        if ((unsigned)gy < 128u) {
            int rb = (rr + ky) << 7;
#pragma unroll
            for (int kx = 0; kx < 3; ++kx) {
                int wx = w + kx - 1;
                if ((unsigned)wx < 128u)
                    acc += wp[ky * 3 + kx] * bf2f(ip[rb + wx]);
            }
        }
    }
    f3[(size_t)z * CH3 * NF + (size_t)c * NF + p] = f2bf(acc);
}

// ---------------------------------------------------------------------------
extern "C" void kernel_launch(void* const* d_in, const int* in_sizes, int n_in,
                              void* d_out, int out_size, void* d_ws, size_t ws_size,
                              hipStream_t stream) {
    const float* x      = (const float*)d_in[0];
    const float* ln1w   = (const float*)d_in[1];
    const float* ln1b   = (const float*)d_in[2];
    const float* qkv_w  = (const float*)d_in[3];
    const float* qkv_b  = (const float*)d_in[4];
    const float* qdw_w  = (const float*)d_in[5];
    const float* qdw_b  = (const float*)d_in[6];
    const float* temp   = (const float*)d_in[7];
    const float* prompt = (const float*)d_in[8];
    const float* proj_w = (const float*)d_in[9];
    const float* proj_b = (const float*)d_in[10];
    const float* ln2w   = (const float*)d_in[11];
    const float* ln2b   = (const float*)d_in[12];
    const float* dw1_w  = (const float*)d_in[13];
    const float* dw1_b  = (const float*)d_in[14];
    const float* pm_w   = (const float*)d_in[15];
    const float* pm_b   = (const float*)d_in[16];
    const float* dw2_w  = (const float*)d_in[17];
    const float* dw2_b  = (const float*)d_in[18];
    const float* po_w   = (const float*)d_in[19];
    const float* po_b   = (const float*)d_in[20];
    float* out = (float*)d_out;   // x2 lives here between proj and po
    (void)in_sizes; (void)n_in; (void)out_size; (void)ws_size;

    // Arena (~40.7 MB, < proven-safe 41.3 MB)
    size_t off = 0;
    char* base = (char*)d_ws;
    auto alloc = [&](size_t bytes) -> char* {
        char* p = base + off;
        off = (off + bytes + 255) & ~(size_t)255;
        return p;
    };
    unsigned short* regionA = (unsigned short*)alloc((size_t)CH3 * HW * 2); // preQKV | attnout | f1,f3
    unsigned short* regionB = (unsigned short*)alloc((size_t)CH3 * HW * 2); // qkvT | f2
    float* G0p  = (float*)alloc((size_t)4 * NSL * 2304 * 4);
    float* Amat = (float*)alloc((size_t)4 * 2304 * 4);
    float* invn = (float*)alloc(384 * 4);
    float* muv  = (float*)alloc((size_t)NGRP * HW * 4);
    float* rsv  = (float*)alloc((size_t)NGRP * HW * 4);

    unsigned short* preQKV  = regionA;
    unsigned short* attnout = regionA;
    unsigned short* f1      = regionA;
    unsigned short* f3      = regionA;   // aliases f1 (f1 dead when dw2 runs)
    unsigned short* qkvT    = regionB;
    unsigned short* f2      = regionB;

    dim3 blk(256);

    // ---------------- phase 1+2: attention, per batch ----------------
    for (int b = 0; b < NB; ++b) {
        const float* xb = x + (size_t)b * CDIM * HW;
        float* x2b      = out + (size_t)b * CDIM * HW;

        ln_stats<<<dim3(64, 1), blk, 0, stream>>>(xb, muv, rsv);

        // qkv 1x1 (LN-fused) -> preQKV bf16   [grid 128x9 = 1152 blocks]
        gemm_mfma<0, 0><<<dim3(HW / 128, CH3 / 64, 1), blk, 0, stream>>>(
            qkv_w, xb, HW, 0, muv, rsv, ln1w, ln1b, qkv_b,
            nullptr, 0, 0, preQKV, HW, 0, CH3, CDIM);

        // depthwise 3x3 + prompt -> qkvT bf16
        dwp<<<dim3(64, CH3), blk, 0, stream>>>(preQKV, qdw_w, qdw_b, prompt, qkvT);

        inv_norms1<<<dim3(384), blk, 0, stream>>>(qkvT, invn);
        gram1<<<dim3(NSL, 4), blk, 0, stream>>>(qkvT, G0p);
        softmax1<<<dim3(4), blk, 0, stream>>>(G0p, invn, temp, Amat);
        apply1<<<dim3(64, 4), blk, 0, stream>>>(qkvT, Amat, attnout);

        // proj 1x1 + residual(x) -> x2 (fp32, in d_out)   [grid 128x3]
        gemm_mfma<1, 2><<<dim3(HW / 128, CDIM / 64, 1), blk, 0, stream>>>(
            proj_w, attnout, HW, 0, nullptr, nullptr, nullptr, nullptr, proj_b,
            xb, HW, 0, x2b, HW, 0, CDIM, CDIM);
    }

    // ---------------- phase 3+4: FFN, groups of NGRP batches ----------------
    for (int g0 = 0; g0 < NB; g0 += NGRP) {
        float* x2g = out + (size_t)g0 * CDIM * HW;

        ln_stats<<<dim3(64, NGRP), blk, 0, stream>>>(x2g, muv, rsv);

        for (int t = 0; t < 128 / TROWS; ++t) {
            int r0 = t * TROWS;
            dwln_tile<<<dim3(NT / 256, CH3, NGRP), blk, 0, stream>>>(
                x2g, muv, rsv, ln2w, ln2b, dw1_w, dw1_b, f1, r0);
            // pm 576->576 + gelu -> f2 bf16   [grid 18x9x4 = 648 blocks]
            gemm_mfma<1, 1><<<dim3(NT / 128, CH3 / 64, NGRP), blk, 0, stream>>>(
                pm_w, f1, NT, (long)CH3 * NT, nullptr, nullptr, nullptr, nullptr, pm_b,
                nullptr, 0, 0, f2, NT, (long)CH3 * NT, CH3, CH3);
            dw2_tile<<<dim3(NF / 256, CH3, NGRP), blk, 0, stream>>>(
                f2, dw2_w, dw2_b, f3, r0);
            // po 576->192 + residual(x2 rows) -> out rows  [grid 16x3x4 = 192]
            gemm_mfma<1, 2><<<dim3(NF / 128, CDIM / 64, NGRP), blk, 0, stream>>>(
                po_w, f3, NF, (long)CH3 * NF, nullptr, nullptr, nullptr, nullptr, po_b,
                x2g + (size_t)r0 * 128, HW, (long)CDIM * HW,
                x2g + (size_t)r0 * 128, HW, (long)CDIM * HW, CDIM, CH3);
        }
    }
}

// Round 2
// 3001.730 us; speedup vs baseline: 1.4642x; 1.2313x over previous
//
#include <hip/hip_runtime.h>

// Problem constants
#define HW     16384      // 128*128
#define NB     8
#define CDIM   192
#define CH3    576
#define NHEADS 4
#define CHH    48
#define TROWS  16           // FFN tile rows
#define TSLOT  18           // + halo
#define NT     (TSLOT*128)  // 2304
#define NF     (TROWS*128)  // 2048
#define LDA    40           // LDS k-stride (bf16 elems): 80B, 16B-mult, 2-way-free banks
#define NSL    64           // gram1 n-slices

typedef short  v8s  __attribute__((ext_vector_type(8)));
typedef float  v4f  __attribute__((ext_vector_type(4)));
typedef unsigned short u16x8 __attribute__((ext_vector_type(8)));

__device__ __forceinline__ float bf2f(unsigned short s) {
    return __uint_as_float(((unsigned)s) << 16);
}
__device__ __forceinline__ unsigned short f2bf(float f) {
    unsigned u = __float_as_uint(f);
    return (unsigned short)((u + 0x7fffu + ((u >> 16) & 1u)) >> 16);
}
__device__ __forceinline__ float gelu_f(float x) {
    return 0.5f * x * (1.0f + erff(x * 0.70710678118654752f));
}

// ---------------------------------------------------------------------------
// LayerNorm -> normalized bf16 tensor xn[z][c][p]. grid (64, Z)
// Second pass re-reads x from L2 (block-local 196KB, cache-resident).
// ---------------------------------------------------------------------------
__global__ __launch_bounds__(256) void ln_norm(const float* __restrict__ x,
                                               const float* __restrict__ lnw,
                                               const float* __restrict__ lnb,
                                               unsigned short* __restrict__ xn) {
    int p = blockIdx.x * 256 + threadIdx.x;
    int z = blockIdx.y;
    const float* xp = x + (size_t)z * CDIM * HW;
    unsigned short* op = xn + (size_t)z * CDIM * HW;
    float s = 0.f, ss = 0.f;
    for (int c = 0; c < CDIM; ++c) {
        float v = xp[(size_t)c * HW + p];
        s += v; ss += v * v;
    }
    float m = s * (1.0f / CDIM);
    float var = ss * (1.0f / CDIM) - m * m;
    float r = 1.0f / sqrtf(var + 1e-5f);
    for (int c = 0; c < CDIM; ++c) {
        float v = (xp[(size_t)c * HW + p] - m) * r * lnw[c] + lnb[c];
        op[(size_t)c * HW + p] = f2bf(v);
    }
}

// ---------------------------------------------------------------------------
// MFMA bf16 GEMM: out[m,n] = sum_k W[m,k] * X[k,n]  (fp32 acc/epilogue)
// Block: 256 thr = 4 waves (2x2), tile M=64 x N=128, K-step 32. X is bf16.
// EPI 0: +bias -> bf16; 1: +bias,gelu -> bf16; 2: +bias,+res(fp32) -> fp32.
// grid (N/128, M/64, Z)
// ---------------------------------------------------------------------------
template <int EPI>
__global__ __launch_bounds__(256) void gemm_mfma(
    const float* __restrict__ Aw,
    const unsigned short* __restrict__ Bin, int b_cs, long b_zs,
    const float* __restrict__ bias,
    const float* __restrict__ res, int r_cs, long r_zs,
    void* __restrict__ outp, int o_cs, long o_zs,
    int M, int K) {
    __shared__ unsigned short Albs[64 * LDA];
    __shared__ unsigned short Blbs[128 * LDA];

    const int t  = threadIdx.x;
    const int n0 = blockIdx.x * 128;
    const int m0 = blockIdx.y * 64;
    const int z  = blockIdx.z;

    const int wid = t >> 6, lane = t & 63;
    const int lm = lane & 15, quad = lane >> 4;
    const int wm = (wid & 1) * 32, wn = (wid >> 1) * 64;

    v4f acc[2][4];
#pragma unroll
    for (int mi = 0; mi < 2; ++mi)
#pragma unroll
        for (int ni = 0; ni < 4; ++ni) acc[mi][ni] = (v4f)0.0f;

    // staging coords
    const int am = t >> 2, kc = (t & 3) << 3;       // A: 64 m x 4 k-chunks of 8
    const int bk = t >> 3, nc = (t & 7) << 4;       // B: 32 k x 8 n-chunks of 16

    for (int k0 = 0; k0 < K; k0 += 32) {
        if (k0) __syncthreads();
        // --- stage A (64 x 32), fp32 -> bf16, layout [m][k] ---
        {
            const float* wp = Aw + (size_t)(m0 + am) * K + k0 + kc;
            float4 w0 = *(const float4*)wp;
            float4 w1 = *(const float4*)(wp + 4);
            u16x8 u;
            u[0] = f2bf(w0.x); u[1] = f2bf(w0.y); u[2] = f2bf(w0.z); u[3] = f2bf(w0.w);
            u[4] = f2bf(w1.x); u[5] = f2bf(w1.y); u[6] = f2bf(w1.z); u[7] = f2bf(w1.w);
            *(u16x8*)&Albs[am * LDA + kc] = u;
        }
        // --- stage B (32 k x 128 n) transposed to [n][k] ---
        {
            const unsigned short* bp = Bin + (size_t)z * b_zs +
                                       (size_t)(k0 + bk) * b_cs + n0 + nc;
            u16x8 u0 = *(const u16x8*)bp;
            u16x8 u1 = *(const u16x8*)(bp + 8);
#pragma unroll
            for (int i = 0; i < 8; ++i) {
                Blbs[(nc + i) * LDA + bk]     = u0[i];
                Blbs[(nc + 8 + i) * LDA + bk] = u1[i];
            }
        }
        __syncthreads();
        // --- 2x4 MFMA 16x16x32 ---
        v8s a[2], b[4];
#pragma unroll
        for (int mi = 0; mi < 2; ++mi)
            a[mi] = *(const v8s*)&Albs[(wm + mi * 16 + lm) * LDA + quad * 8];
#pragma unroll
        for (int ni = 0; ni < 4; ++ni)
            b[ni] = *(const v8s*)&Blbs[(wn + ni * 16 + lm) * LDA + quad * 8];
#pragma unroll
        for (int mi = 0; mi < 2; ++mi)
#pragma unroll
            for (int ni = 0; ni < 4; ++ni)
                acc[mi][ni] = __builtin_amdgcn_mfma_f32_16x16x32_bf16(
                    a[mi], b[ni], acc[mi][ni], 0, 0, 0);
    }

    // --- epilogue: D row = quad*4+r, col = lm ---
#pragma unroll
    for (int mi = 0; mi < 2; ++mi)
#pragma unroll
        for (int ni = 0; ni < 4; ++ni)
#pragma unroll
            for (int r = 0; r < 4; ++r) {
                int gm = m0 + wm + mi * 16 + quad * 4 + r;
                int gn = n0 + wn + ni * 16 + lm;
                float v = acc[mi][ni][r] + bias[gm];
                if (EPI == 1) v = gelu_f(v);
                if (EPI == 2) {
                    size_t ri = (size_t)z * r_zs + (size_t)gm * r_cs + gn;
                    size_t oi = (size_t)z * o_zs + (size_t)gm * o_cs + gn;
                    ((float*)outp)[oi] = v + res[ri];
                } else {
                    size_t oi = (size_t)z * o_zs + (size_t)gm * o_cs + gn;
                    ((unsigned short*)outp)[oi] = f2bf(v);
                }
            }
}

// ---------------------------------------------------------------------------
// Depthwise 3x3 (pad=1) + bias + prompt[c%192] on 576-ch bf16. grid (64,576,Z)
// ---------------------------------------------------------------------------
__global__ __launch_bounds__(256) void dwp(const unsigned short* __restrict__ in,
                                           const float* __restrict__ w9,
                                           const float* __restrict__ b1,
                                           const float* __restrict__ prompt,
                                           unsigned short* __restrict__ out) {
    int p = blockIdx.x * 256 + threadIdx.x;
    int c = blockIdx.y;
    int z = blockIdx.z;
    int h = p >> 7, w = p & 127;
    const unsigned short* ip = in + (size_t)z * CH3 * HW + (size_t)c * HW;
    const float* wp = w9 + c * 9;
    float acc = b1[c] + prompt[c % CDIM];
#pragma unroll
    for (int ky = 0; ky < 3; ++ky) {
        int hy = h + ky - 1;
        if ((unsigned)hy < 128u) {
            int rb = hy << 7;
#pragma unroll
            for (int kx = 0; kx < 3; ++kx) {
                int wx = w + kx - 1;
                if ((unsigned)wx < 128u)
                    acc += wp[ky * 3 + kx] * bf2f(ip[rb + wx]);
            }
        }
    }
    out[(size_t)z * CH3 * HW + (size_t)c * HW + p] = f2bf(acc);
}

// ---------------------------------------------------------------------------
// 1/max(L2norm,1e-12) per q,k channel (0..383). grid (384, Z)
// ---------------------------------------------------------------------------
__global__ __launch_bounds__(256) void inv_norms1(const unsigned short* __restrict__ qk,
                                                  float* __restrict__ invn) {
    int ch = blockIdx.x;
    int z = blockIdx.y;
    const unsigned short* p = qk + (size_t)z * CH3 * HW + (size_t)ch * HW;
    float ss = 0.f;
    for (int i = threadIdx.x; i < HW; i += 256) { float v = bf2f(p[i]); ss += v * v; }
    __shared__ float r[256];
    r[threadIdx.x] = ss;
    __syncthreads();
    for (int off = 128; off; off >>= 1) {
        if (threadIdx.x < (unsigned)off) r[threadIdx.x] += r[threadIdx.x + off];
        __syncthreads();
    }
    if (threadIdx.x == 0) invn[z * 384 + ch] = 1.0f / fmaxf(sqrtf(r[0]), 1e-12f);
}

// ---------------------------------------------------------------------------
// Gram partials via MFMA: G0p[((z*4+h)*NSL + sl)][qc*48+kc].
// grid (NSL, 4 heads, Z), 256 thr = 4 waves.
// ---------------------------------------------------------------------------
__global__ __launch_bounds__(256) void gram1(const unsigned short* __restrict__ qk,
                                             float* __restrict__ G0p) {
    const int sl = blockIdx.x, h = blockIdx.y, z = blockIdx.z;
    const int t = threadIdx.x;
    const int wid = t >> 6, lane = t & 63;
    const int lm = lane & 15, quad = lane >> 4;

    const unsigned short* qb = qk + (size_t)z * CH3 * HW + (size_t)(h * CHH) * HW;
    const unsigned short* kb = qk + (size_t)z * CH3 * HW + (size_t)(192 + h * CHH) * HW;

    v4f acc[3][3];
#pragma unroll
    for (int mi = 0; mi < 3; ++mi)
#pragma unroll
        for (int ni = 0; ni < 3; ++ni) acc[mi][ni] = (v4f)0.0f;

    // wave covers n in [sl*256 + wid*64, +64): two K-steps of 32
    const int nbase = sl * 256 + wid * 64 + quad * 8;
#pragma unroll
    for (int ks = 0; ks < 2; ++ks) {
        const int n = nbase + ks * 32;
        v8s a[3], b[3];
#pragma unroll
        for (int i = 0; i < 3; ++i) {
            a[i] = *(const v8s*)(qb + (size_t)(i * 16 + lm) * HW + n);
            b[i] = *(const v8s*)(kb + (size_t)(i * 16 + lm) * HW + n);
        }
#pragma unroll
        for (int mi = 0; mi < 3; ++mi)
#pragma unroll
            for (int ni = 0; ni < 3; ++ni)
                acc[mi][ni] = __builtin_amdgcn_mfma_f32_16x16x32_bf16(
                    a[mi], b[ni], acc[mi][ni], 0, 0, 0);
    }

    // cross-wave reduce in LDS, one fp32 partial per block
    __shared__ float Gs[4][2304];
#pragma unroll
    for (int mi = 0; mi < 3; ++mi)
#pragma unroll
        for (int ni = 0; ni < 3; ++ni)
#pragma unroll
            for (int r = 0; r < 4; ++r)
                Gs[wid][(mi * 16 + quad * 4 + r) * 48 + ni * 16 + lm] = acc[mi][ni][r];
    __syncthreads();
    float* gp = G0p + (((size_t)z * NHEADS + h) * NSL + sl) * 2304;
    for (int i = t; i < 2304; i += 256)
        gp[i] = Gs[0][i] + Gs[1][i] + Gs[2][i] + Gs[3][i];
}

// ---------------------------------------------------------------------------
// logits = T*G*invq*invk; softmax over d. grid (4, Z) x 256 thr, NSL partials
// ---------------------------------------------------------------------------
__global__ __launch_bounds__(256) void softmax1(const float* __restrict__ G0p,
                                                const float* __restrict__ invn,
                                                const float* __restrict__ temp,
                                                float* __restrict__ Amat) {
    int h = blockIdx.x;
    int z = blockIdx.y;
    int t = threadIdx.x;
    __shared__ float Gs[2304];
    const float* gbase = G0p + ((size_t)z * NHEADS + h) * NSL * 2304;
    for (int i = t; i < 2304; i += 256) {
        float s = 0.f;
#pragma unroll 8
        for (int sl = 0; sl < NSL; ++sl) s += gbase[(size_t)sl * 2304 + i];
        Gs[i] = s;
    }
    __syncthreads();
    if (t < 48) {
        float T = temp[h];
        const float* iv = invn + (size_t)z * 384;
        float invq = iv[h * CHH + t];
        const float* gr = &Gs[t * 48];
        float lg[48];
        float mx = -1e30f;
#pragma unroll
        for (int d = 0; d < 48; ++d) {
            float l = T * gr[d] * invq * iv[192 + h * CHH + d];
            lg[d] = l;
            mx = fmaxf(mx, l);
        }
        float sum = 0.f;
#pragma unroll
        for (int d = 0; d < 48; ++d) { float e = expf(lg[d] - mx); lg[d] = e; sum += e; }
        float inv = 1.0f / sum;
        float* ap = Amat + ((size_t)z * NHEADS + h) * 2304 + t * 48;
#pragma unroll
        for (int d = 0; d < 48; ++d) ap[d] = lg[d] * inv;
    }
}

// ---------------------------------------------------------------------------
// attnout[c,n] = sum_d A[c,d]*v~[d,n] per head (bf16 in/out). grid (64, 4, Z)
// ---------------------------------------------------------------------------
__global__ __launch_bounds__(256) void apply1(const unsigned short* __restrict__ qkvT,
                                              const float* __restrict__ Amat,
                                              unsigned short* __restrict__ attnout) {
    int n = blockIdx.x * 256 + threadIdx.x;
    int h = blockIdx.y;
    int z = blockIdx.z;
    __shared__ float As[2304];
    for (int i = threadIdx.x; i < 2304; i += 256)
        As[i] = Amat[((size_t)z * NHEADS + h) * 2304 + i];
    __syncthreads();
    const unsigned short* vp = qkvT + (size_t)z * CH3 * HW + (size_t)(384 + h * CHH) * HW + n;
    float acc[48];
#pragma unroll
    for (int c = 0; c < 48; ++c) acc[c] = 0.f;
    for (int d = 0; d < 48; ++d) {
        float v = bf2f(vp[(size_t)d * HW]);
#pragma unroll
        for (int c = 0; c < 48; ++c) acc[c] = fmaf(As[c * 48 + d], v, acc[c]);
    }
    unsigned short* op = attnout + (size_t)z * CDIM * HW + (size_t)(h * CHH) * HW + n;
#pragma unroll
    for (int c = 0; c < 48; ++c) op[(size_t)c * HW] = f2bf(acc[c]);
}

// ---------------------------------------------------------------------------
// FFN grouped 3x3 (192->576) on pre-normalized bf16 xn, row-tile +halo.
// grid (NT/256, 576, Z). Junk (finite) for invalid global rows.
// ---------------------------------------------------------------------------
__global__ __launch_bounds__(256) void dw1_tile(const unsigned short* __restrict__ xn,
                                                const float* __restrict__ w9,
                                                const float* __restrict__ b1,
                                                unsigned short* __restrict__ f1, int r0) {
    int p = blockIdx.x * 256 + threadIdx.x;   // 0..NT-1
    int c = blockIdx.y, z = blockIdx.z;
    int s = p >> 7, w = p & 127;
    int gr = r0 - 1 + s;
    int g = c / 3;
    const unsigned short* ip = xn + (size_t)z * CDIM * HW + (size_t)g * HW;
    const float* wp = w9 + c * 9;
    float acc = b1[c];
#pragma unroll
    for (int ky = 0; ky < 3; ++ky) {
        int hy = gr + ky - 1;
        if ((unsigned)hy < 128u) {
            int rb = hy << 7;
#pragma unroll
            for (int kx = 0; kx < 3; ++kx) {
                int wx = w + kx - 1;
                if ((unsigned)wx < 128u)
                    acc += wp[ky * 3 + kx] * bf2f(ip[rb + wx]);
            }
        }
    }
    f1[(size_t)z * CH3 * NT + (size_t)c * NT + p] = f2bf(acc);
}

// ---------------------------------------------------------------------------
// FFN depthwise 3x3 on f2 tile -> f3, z-batched. grid (NF/256, 576, Z)
// ---------------------------------------------------------------------------
__global__ __launch_bounds__(256) void dw2_tile(const unsigned short* __restrict__ f2,
                                                const float* __restrict__ w9,
                                                const float* __restrict__ b1,
                                                unsigned short* __restrict__ f3, int r0) {
    int p = blockIdx.x * 256 + threadIdx.x;   // 0..NF-1
    int c = blockIdx.y, z = blockIdx.z;
    int rr = p >> 7, w = p & 127;
    const unsigned short* ip = f2 + (size_t)z * CH3 * NT + (size_t)c * NT;
    const float* wp = w9 + c * 9;
    float acc = b1[c];
#pragma unroll
    for (int ky = 0; ky < 3; ++ky) {
        int gy = r0 + rr + ky - 1;
        if ((unsigned)gy < 128u) {
            int rb = (rr + ky) << 7;
#pragma unroll
            for (int kx = 0; kx < 3; ++kx) {
                int wx = w + kx - 1;
                if ((unsigned)wx < 128u)
                    acc += wp[ky * 3 + kx] * bf2f(ip[rb + wx]);
            }
        }
    }
    f3[(size_t)z * CH3 * NF + (size_t)c * NF + p] = f2bf(acc);
}

// ---------------------------------------------------------------------------
extern "C" void kernel_launch(void* const* d_in, const int* in_sizes, int n_in,
                              void* d_out, int out_size, void* d_ws, size_t ws_size,
                              hipStream_t stream) {
    const float* x      = (const float*)d_in[0];
    const float* ln1w   = (const float*)d_in[1];
    const float* ln1b   = (const float*)d_in[2];
    const float* qkv_w  = (const float*)d_in[3];
    const float* qkv_b  = (const float*)d_in[4];
    const float* qdw_w  = (const float*)d_in[5];
    const float* qdw_b  = (const float*)d_in[6];
    const float* temp   = (const float*)d_in[7];
    const float* prompt = (const float*)d_in[8];
    const float* proj_w = (const float*)d_in[9];
    const float* proj_b = (const float*)d_in[10];
    const float* ln2w   = (const float*)d_in[11];
    const float* ln2b   = (const float*)d_in[12];
    const float* dw1_w  = (const float*)d_in[13];
    const float* dw1_b  = (const float*)d_in[14];
    const float* pm_w   = (const float*)d_in[15];
    const float* pm_b   = (const float*)d_in[16];
    const float* dw2_w  = (const float*)d_in[17];
    const float* dw2_b  = (const float*)d_in[18];
    const float* po_w   = (const float*)d_in[19];
    const float* po_b   = (const float*)d_in[20];
    float* out = (float*)d_out;   // x2 lives here between proj and po
    (void)in_sizes; (void)n_in; (void)out_size;

    // ---- pick phase-1 group size PG and FFN group size NG to fit ws_size ----
    auto al = [](size_t b) { return (b + 255) & ~(size_t)255; };
    auto need = [&](int PG, int NG) -> size_t {
        size_t rA = al((size_t)PG * CH3 * HW * 2);
        size_t rB_attn = (size_t)PG * CH3 * HW * 2;
        size_t rB_ffn = (size_t)NG * CDIM * HW * 2 + (size_t)NG * CH3 * NT * 2;
        size_t rB = al(rB_attn > rB_ffn ? rB_attn : rB_ffn);
        return rA + rB + al((size_t)PG * NHEADS * NSL * 2304 * 4) +
               al((size_t)PG * NHEADS * 2304 * 4) + al((size_t)PG * 384 * 4) + 4096;
    };
    int PG = 8, NG = 4;
    if (need(PG, NG) > ws_size) { PG = 2; NG = 4; }
    if (need(PG, NG) > ws_size) { PG = 1; NG = 2; }

    // ---- arena ----
    size_t off = 0;
    char* base = (char*)d_ws;
    auto alloc = [&](size_t bytes) -> char* {
        char* p = base + off;
        off = (off + bytes + 255) & ~(size_t)255;
        return p;
    };
    size_t rB_attn = (size_t)PG * CH3 * HW * 2;
    size_t rB_ffn  = (size_t)NG * CDIM * HW * 2 + (size_t)NG * CH3 * NT * 2;
    unsigned short* regionA = (unsigned short*)alloc((size_t)PG * CH3 * HW * 2);
    unsigned short* regionB = (unsigned short*)alloc(rB_attn > rB_ffn ? rB_attn : rB_ffn);
    float* G0p  = (float*)alloc((size_t)PG * NHEADS * NSL * 2304 * 4);
    float* Amat = (float*)alloc((size_t)PG * NHEADS * 2304 * 4);
    float* invn = (float*)alloc((size_t)PG * 384 * 4);

    unsigned short* preQKV  = regionA;                 // [z][576][HW] bf16
    unsigned short* attnout = regionA;                 // [z][192][HW] bf16 (preQKV dead)
    unsigned short* f1      = regionA;                 // [z][576][NT] bf16 (FFN)
    unsigned short* f3      = regionA;                 // aliases f1
    unsigned short* xnA     = regionB;                 // [z][192][HW] bf16 (attn LN)
    unsigned short* qkvT    = regionB;                 // [z][576][HW] bf16 (xn dead)
    unsigned short* xnF     = regionB;                 // [z][192][HW] bf16 (FFN LN)
    unsigned short* f2      = regionB + (size_t)NG * CDIM * HW;  // [z][576][NT] bf16

    dim3 blk(256);

    // ---------------- phase 1+2: attention, PG batches at a time ----------------
    for (int b0 = 0; b0 < NB; b0 += PG) {
        const float* xb = x + (size_t)b0 * CDIM * HW;
        float* x2b      = out + (size_t)b0 * CDIM * HW;

        // LN1 -> xnA bf16
        ln_norm<<<dim3(64, PG), blk, 0, stream>>>(xb, ln1w, ln1b, xnA);

        // qkv 1x1 -> preQKV bf16   [grid 128x9xPG]
        gemm_mfma<0><<<dim3(HW / 128, CH3 / 64, PG), blk, 0, stream>>>(
            qkv_w, xnA, HW, (long)CDIM * HW, qkv_b,
            nullptr, 0, 0, preQKV, HW, (long)CH3 * HW, CH3, CDIM);

        // depthwise 3x3 + prompt -> qkvT bf16 (overwrites xnA, already consumed)
        dwp<<<dim3(64, CH3, PG), blk, 0, stream>>>(preQKV, qdw_w, qdw_b, prompt, qkvT);

        inv_norms1<<<dim3(384, PG), blk, 0, stream>>>(qkvT, invn);
        gram1<<<dim3(NSL, NHEADS, PG), blk, 0, stream>>>(qkvT, G0p);
        softmax1<<<dim3(NHEADS, PG), blk, 0, stream>>>(G0p, invn, temp, Amat);
        apply1<<<dim3(64, NHEADS, PG), blk, 0, stream>>>(qkvT, Amat, attnout);

        // proj 1x1 + residual(x) -> x2 (fp32, in d_out)   [grid 128x3xPG]
        gemm_mfma<2><<<dim3(HW / 128, CDIM / 64, PG), blk, 0, stream>>>(
            proj_w, attnout, HW, (long)CDIM * HW, proj_b,
            xb, HW, (long)CDIM * HW, x2b, HW, (long)CDIM * HW, CDIM, CDIM);
    }

    // ---------------- phase 3+4: FFN, groups of NG batches ----------------
    for (int g0 = 0; g0 < NB; g0 += NG) {
        float* x2g = out + (size_t)g0 * CDIM * HW;

        // LN2 -> xnF bf16
        ln_norm<<<dim3(64, NG), blk, 0, stream>>>(x2g, ln2w, ln2b, xnF);

        for (int t = 0; t < 128 / TROWS; ++t) {
            int r0 = t * TROWS;
            dw1_tile<<<dim3(NT / 256, CH3, NG), blk, 0, stream>>>(
                xnF, dw1_w, dw1_b, f1, r0);
            // pm 576->576 + gelu -> f2 bf16   [grid 18x9xNG]
            gemm_mfma<1><<<dim3(NT / 128, CH3 / 64, NG), blk, 0, stream>>>(
                pm_w, f1, NT, (long)CH3 * NT, pm_b,
                nullptr, 0, 0, f2, NT, (long)CH3 * NT, CH3, CH3);
            dw2_tile<<<dim3(NF / 256, CH3, NG), blk, 0, stream>>>(
                f2, dw2_w, dw2_b, f3, r0);
            // po 576->192 + residual(x2 rows) -> out rows  [grid 16x3xNG]
            gemm_mfma<2><<<dim3(NF / 128, CDIM / 64, NG), blk, 0, stream>>>(
                po_w, f3, NF, (long)CH3 * NF, po_b,
                x2g + (size_t)r0 * 128, HW, (long)CDIM * HW,
                x2g + (size_t)r0 * 128, HW, (long)CDIM * HW, CDIM, CH3);
        }
    }
}

// Round 3
// 2230.814 us; speedup vs baseline: 1.9702x; 1.3456x over previous
//
#include <hip/hip_runtime.h>

// Problem constants
#define HW     16384      // 128*128
#define NB     8
#define CDIM   192
#define CH3    576
#define NHEADS 4
#define CHH    48
#define TROWS  16           // FFN tile rows
#define TSLOT  18           // + halo
#define NT     (TSLOT*128)  // 2304
#define NF     (TROWS*128)  // 2048
#define LDA    40           // LDS k-stride (bf16 elems): 80B, 16B-mult, 2-way-free banks
#define NSL    64           // gram1 n-slices

typedef short  v8s  __attribute__((ext_vector_type(8)));
typedef float  v4f  __attribute__((ext_vector_type(4)));
typedef unsigned short u16x8 __attribute__((ext_vector_type(8)));

__device__ __forceinline__ float bf2f(unsigned short s) {
    return __uint_as_float(((unsigned)s) << 16);
}
__device__ __forceinline__ unsigned short f2bf(float f) {
    unsigned u = __float_as_uint(f);
    return (unsigned short)((u + 0x7fffu + ((u >> 16) & 1u)) >> 16);
}
__device__ __forceinline__ float gelu_f(float x) {
    return 0.5f * x * (1.0f + erff(x * 0.70710678118654752f));
}

// Vectorized 3x3 row update: acc[0..7] += taps of row [w0-1, w0+8]
__device__ __forceinline__ void dw_row(float acc[8], const unsigned short* __restrict__ row,
                                       int w0, float wl, float wc, float wr) {
    u16x8 m = *(const u16x8*)row;
    float mv[8];
#pragma unroll
    for (int j = 0; j < 8; ++j) mv[j] = bf2f(m[j]);
    float lft = (w0 > 0)   ? bf2f(row[-1]) : 0.f;
    float rgt = (w0 < 120) ? bf2f(row[8])  : 0.f;
    acc[0] = fmaf(wl, lft, acc[0]);
#pragma unroll
    for (int j = 1; j < 8; ++j) acc[j] = fmaf(wl, mv[j - 1], acc[j]);
#pragma unroll
    for (int j = 0; j < 8; ++j) acc[j] = fmaf(wc, mv[j], acc[j]);
#pragma unroll
    for (int j = 0; j < 7; ++j) acc[j] = fmaf(wr, mv[j + 1], acc[j]);
    acc[7] = fmaf(wr, rgt, acc[7]);
}

// ---------------------------------------------------------------------------
// LayerNorm -> normalized bf16 tensor xn[z][c][p]. grid (64, Z)
// ---------------------------------------------------------------------------
__global__ __launch_bounds__(256) void ln_norm(const float* __restrict__ x,
                                               const float* __restrict__ lnw,
                                               const float* __restrict__ lnb,
                                               unsigned short* __restrict__ xn) {
    int p = blockIdx.x * 256 + threadIdx.x;
    int z = blockIdx.y;
    const float* xp = x + (size_t)z * CDIM * HW;
    unsigned short* op = xn + (size_t)z * CDIM * HW;
    float s = 0.f, ss = 0.f;
    for (int c = 0; c < CDIM; ++c) {
        float v = xp[(size_t)c * HW + p];
        s += v; ss += v * v;
    }
    float m = s * (1.0f / CDIM);
    float var = ss * (1.0f / CDIM) - m * m;
    float r = 1.0f / sqrtf(var + 1e-5f);
    for (int c = 0; c < CDIM; ++c) {
        float v = (xp[(size_t)c * HW + p] - m) * r * lnw[c] + lnb[c];
        op[(size_t)c * HW + p] = f2bf(v);
    }
}

// ---------------------------------------------------------------------------
// MFMA bf16 GEMM: out[m,n] = sum_k W[m,k] * X[k,n]  (fp32 acc/epilogue)
// Block: 256 thr = 4 waves (2x2), tile M=64 x N=128, K-step 32. X is bf16.
// EPI 0: +bias -> bf16; 1: +bias,gelu -> bf16; 2: +bias,+res(fp32) -> fp32.
// grid (N/128, M/64, Z)
// ---------------------------------------------------------------------------
template <int EPI>
__global__ __launch_bounds__(256) void gemm_mfma(
    const float* __restrict__ Aw,
    const unsigned short* __restrict__ Bin, int b_cs, long b_zs,
    const float* __restrict__ bias,
    const float* __restrict__ res, int r_cs, long r_zs,
    void* __restrict__ outp, int o_cs, long o_zs,
    int M, int K) {
    __shared__ unsigned short Albs[64 * LDA];
    __shared__ unsigned short Blbs[128 * LDA];

    const int t  = threadIdx.x;
    const int n0 = blockIdx.x * 128;
    const int m0 = blockIdx.y * 64;
    const int z  = blockIdx.z;

    const int wid = t >> 6, lane = t & 63;
    const int lm = lane & 15, quad = lane >> 4;
    const int wm = (wid & 1) * 32, wn = (wid >> 1) * 64;

    v4f acc[2][4];
#pragma unroll
    for (int mi = 0; mi < 2; ++mi)
#pragma unroll
        for (int ni = 0; ni < 4; ++ni) acc[mi][ni] = (v4f)0.0f;

    // staging coords
    const int am = t >> 2, kc = (t & 3) << 3;       // A: 64 m x 4 k-chunks of 8
    const int bk = t >> 3, nc = (t & 7) << 4;       // B: 32 k x 8 n-chunks of 16

    for (int k0 = 0; k0 < K; k0 += 32) {
        if (k0) __syncthreads();
        // --- stage A (64 x 32), fp32 -> bf16, layout [m][k] ---
        {
            const float* wp = Aw + (size_t)(m0 + am) * K + k0 + kc;
            float4 w0 = *(const float4*)wp;
            float4 w1 = *(const float4*)(wp + 4);
            u16x8 u;
            u[0] = f2bf(w0.x); u[1] = f2bf(w0.y); u[2] = f2bf(w0.z); u[3] = f2bf(w0.w);
            u[4] = f2bf(w1.x); u[5] = f2bf(w1.y); u[6] = f2bf(w1.z); u[7] = f2bf(w1.w);
            *(u16x8*)&Albs[am * LDA + kc] = u;
        }
        // --- stage B (32 k x 128 n) transposed to [n][k] ---
        {
            const unsigned short* bp = Bin + (size_t)z * b_zs +
                                       (size_t)(k0 + bk) * b_cs + n0 + nc;
            u16x8 u0 = *(const u16x8*)bp;
            u16x8 u1 = *(const u16x8*)(bp + 8);
#pragma unroll
            for (int i = 0; i < 8; ++i) {
                Blbs[(nc + i) * LDA + bk]     = u0[i];
                Blbs[(nc + 8 + i) * LDA + bk] = u1[i];
            }
        }
        __syncthreads();
        // --- 2x4 MFMA 16x16x32 ---
        v8s a[2], b[4];
#pragma unroll
        for (int mi = 0; mi < 2; ++mi)
            a[mi] = *(const v8s*)&Albs[(wm + mi * 16 + lm) * LDA + quad * 8];
#pragma unroll
        for (int ni = 0; ni < 4; ++ni)
            b[ni] = *(const v8s*)&Blbs[(wn + ni * 16 + lm) * LDA + quad * 8];
#pragma unroll
        for (int mi = 0; mi < 2; ++mi)
#pragma unroll
            for (int ni = 0; ni < 4; ++ni)
                acc[mi][ni] = __builtin_amdgcn_mfma_f32_16x16x32_bf16(
                    a[mi], b[ni], acc[mi][ni], 0, 0, 0);
    }

    // --- epilogue: D row = quad*4+r, col = lm ---
#pragma unroll
    for (int mi = 0; mi < 2; ++mi)
#pragma unroll
        for (int ni = 0; ni < 4; ++ni)
#pragma unroll
            for (int r = 0; r < 4; ++r) {
                int gm = m0 + wm + mi * 16 + quad * 4 + r;
                int gn = n0 + wn + ni * 16 + lm;
                float v = acc[mi][ni][r] + bias[gm];
                if (EPI == 1) v = gelu_f(v);
                if (EPI == 2) {
                    size_t ri = (size_t)z * r_zs + (size_t)gm * r_cs + gn;
                    size_t oi = (size_t)z * o_zs + (size_t)gm * o_cs + gn;
                    ((float*)outp)[oi] = v + res[ri];
                } else {
                    size_t oi = (size_t)z * o_zs + (size_t)gm * o_cs + gn;
                    ((unsigned short*)outp)[oi] = f2bf(v);
                }
            }
}

// ---------------------------------------------------------------------------
// Depthwise 3x3 (pad=1) + bias + prompt[c%192], vectorized 8 px/thread.
// grid (8, 576, Z)
// ---------------------------------------------------------------------------
__global__ __launch_bounds__(256) void dwp(const unsigned short* __restrict__ in,
                                           const float* __restrict__ w9,
                                           const float* __restrict__ b1,
                                           const float* __restrict__ prompt,
                                           unsigned short* __restrict__ out) {
    int slot = blockIdx.x * 256 + threadIdx.x;   // 0..2047
    int c = blockIdx.y;
    int z = blockIdx.z;
    int h = slot >> 4;            // row 0..127
    int w0 = (slot & 15) << 3;    // col base (mult of 8)
    const unsigned short* ip = in + (size_t)z * CH3 * HW + (size_t)c * HW;
    const float* wp = w9 + c * 9;
    float base = b1[c] + prompt[c % CDIM];
    float acc[8];
#pragma unroll
    for (int j = 0; j < 8; ++j) acc[j] = base;
#pragma unroll
    for (int ky = 0; ky < 3; ++ky) {
        int hy = h + ky - 1;
        if ((unsigned)hy < 128u)
            dw_row(acc, ip + (hy << 7) + w0, w0,
                   wp[ky * 3 + 0], wp[ky * 3 + 1], wp[ky * 3 + 2]);
    }
    u16x8 o;
#pragma unroll
    for (int j = 0; j < 8; ++j) o[j] = f2bf(acc[j]);
    *(u16x8*)(out + (size_t)z * CH3 * HW + (size_t)c * HW + (h << 7) + w0) = o;
}

// ---------------------------------------------------------------------------
// 1/max(L2norm,1e-12) per q,k channel (0..383). grid (384, Z)
// ---------------------------------------------------------------------------
__global__ __launch_bounds__(256) void inv_norms1(const unsigned short* __restrict__ qk,
                                                  float* __restrict__ invn) {
    int ch = blockIdx.x;
    int z = blockIdx.y;
    const unsigned short* p = qk + (size_t)z * CH3 * HW + (size_t)ch * HW;
    float ss = 0.f;
    for (int i = threadIdx.x; i < HW; i += 256) { float v = bf2f(p[i]); ss += v * v; }
    __shared__ float r[256];
    r[threadIdx.x] = ss;
    __syncthreads();
    for (int off = 128; off; off >>= 1) {
        if (threadIdx.x < (unsigned)off) r[threadIdx.x] += r[threadIdx.x + off];
        __syncthreads();
    }
    if (threadIdx.x == 0) invn[z * 384 + ch] = 1.0f / fmaxf(sqrtf(r[0]), 1e-12f);
}

// ---------------------------------------------------------------------------
// Gram partials via MFMA: G0p[((z*4+h)*NSL + sl)][qc*48+kc].
// grid (NSL, 4 heads, Z), 256 thr = 4 waves.
// ---------------------------------------------------------------------------
__global__ __launch_bounds__(256) void gram1(const unsigned short* __restrict__ qk,
                                             float* __restrict__ G0p) {
    const int sl = blockIdx.x, h = blockIdx.y, z = blockIdx.z;
    const int t = threadIdx.x;
    const int wid = t >> 6, lane = t & 63;
    const int lm = lane & 15, quad = lane >> 4;

    const unsigned short* qb = qk + (size_t)z * CH3 * HW + (size_t)(h * CHH) * HW;
    const unsigned short* kb = qk + (size_t)z * CH3 * HW + (size_t)(192 + h * CHH) * HW;

    v4f acc[3][3];
#pragma unroll
    for (int mi = 0; mi < 3; ++mi)
#pragma unroll
        for (int ni = 0; ni < 3; ++ni) acc[mi][ni] = (v4f)0.0f;

    // wave covers n in [sl*256 + wid*64, +64): two K-steps of 32
    const int nbase = sl * 256 + wid * 64 + quad * 8;
#pragma unroll
    for (int ks = 0; ks < 2; ++ks) {
        const int n = nbase + ks * 32;
        v8s a[3], b[3];
#pragma unroll
        for (int i = 0; i < 3; ++i) {
            a[i] = *(const v8s*)(qb + (size_t)(i * 16 + lm) * HW + n);
            b[i] = *(const v8s*)(kb + (size_t)(i * 16 + lm) * HW + n);
        }
#pragma unroll
        for (int mi = 0; mi < 3; ++mi)
#pragma unroll
            for (int ni = 0; ni < 3; ++ni)
                acc[mi][ni] = __builtin_amdgcn_mfma_f32_16x16x32_bf16(
                    a[mi], b[ni], acc[mi][ni], 0, 0, 0);
    }

    // cross-wave reduce in LDS, one fp32 partial per block
    __shared__ float Gs[4][2304];
#pragma unroll
    for (int mi = 0; mi < 3; ++mi)
#pragma unroll
        for (int ni = 0; ni < 3; ++ni)
#pragma unroll
            for (int r = 0; r < 4; ++r)
                Gs[wid][(mi * 16 + quad * 4 + r) * 48 + ni * 16 + lm] = acc[mi][ni][r];
    __syncthreads();
    float* gp = G0p + (((size_t)z * NHEADS + h) * NSL + sl) * 2304;
    for (int i = t; i < 2304; i += 256)
        gp[i] = Gs[0][i] + Gs[1][i] + Gs[2][i] + Gs[3][i];
}

// ---------------------------------------------------------------------------
// logits = T*G*invq*invk; softmax over d. grid (4, Z) x 256 thr, NSL partials
// ---------------------------------------------------------------------------
__global__ __launch_bounds__(256) void softmax1(const float* __restrict__ G0p,
                                                const float* __restrict__ invn,
                                                const float* __restrict__ temp,
                                                float* __restrict__ Amat) {
    int h = blockIdx.x;
    int z = blockIdx.y;
    int t = threadIdx.x;
    __shared__ float Gs[2304];
    const float* gbase = G0p + ((size_t)z * NHEADS + h) * NSL * 2304;
    for (int i = t; i < 2304; i += 256) {
        float s = 0.f;
#pragma unroll 8
        for (int sl = 0; sl < NSL; ++sl) s += gbase[(size_t)sl * 2304 + i];
        Gs[i] = s;
    }
    __syncthreads();
    if (t < 48) {
        float T = temp[h];
        const float* iv = invn + (size_t)z * 384;
        float invq = iv[h * CHH + t];
        const float* gr = &Gs[t * 48];
        float lg[48];
        float mx = -1e30f;
#pragma unroll
        for (int d = 0; d < 48; ++d) {
            float l = T * gr[d] * invq * iv[192 + h * CHH + d];
            lg[d] = l;
            mx = fmaxf(mx, l);
        }
        float sum = 0.f;
#pragma unroll
        for (int d = 0; d < 48; ++d) { float e = expf(lg[d] - mx); lg[d] = e; sum += e; }
        float inv = 1.0f / sum;
        float* ap = Amat + ((size_t)z * NHEADS + h) * 2304 + t * 48;
#pragma unroll
        for (int d = 0; d < 48; ++d) ap[d] = lg[d] * inv;
    }
}

// ---------------------------------------------------------------------------
// attnout[c,n] = sum_d A[c,d]*v~[d,n] per head (bf16 in/out). grid (64, 4, Z)
// ---------------------------------------------------------------------------
__global__ __launch_bounds__(256) void apply1(const unsigned short* __restrict__ qkvT,
                                              const float* __restrict__ Amat,
                                              unsigned short* __restrict__ attnout) {
    int n = blockIdx.x * 256 + threadIdx.x;
    int h = blockIdx.y;
    int z = blockIdx.z;
    __shared__ float As[2304];
    for (int i = threadIdx.x; i < 2304; i += 256)
        As[i] = Amat[((size_t)z * NHEADS + h) * 2304 + i];
    __syncthreads();
    const unsigned short* vp = qkvT + (size_t)z * CH3 * HW + (size_t)(384 + h * CHH) * HW + n;
    float acc[48];
#pragma unroll
    for (int c = 0; c < 48; ++c) acc[c] = 0.f;
    for (int d = 0; d < 48; ++d) {
        float v = bf2f(vp[(size_t)d * HW]);
#pragma unroll
        for (int c = 0; c < 48; ++c) acc[c] = fmaf(As[c * 48 + d], v, acc[c]);
    }
    unsigned short* op = attnout + (size_t)z * CDIM * HW + (size_t)(h * CHH) * HW + n;
#pragma unroll
    for (int c = 0; c < 48; ++c) op[(size_t)c * HW] = f2bf(acc[c]);
}

// ---------------------------------------------------------------------------
// FFN grouped 3x3 (192->576) on pre-normalized bf16 xn, row-tile +halo,
// vectorized 8 px/thread. grid (648, Z): idx -> c (0..575), slot (0..287).
// ---------------------------------------------------------------------------
__global__ __launch_bounds__(256) void dw1_tile(const unsigned short* __restrict__ xn,
                                                const float* __restrict__ w9,
                                                const float* __restrict__ b1,
                                                unsigned short* __restrict__ f1, int r0) {
    int idx = blockIdx.x * 256 + threadIdx.x;   // 0..165887
    int z = blockIdx.y;
    int c = idx / 288;
    int slot = idx - c * 288;
    int s = slot >> 4;            // tile row 0..17
    int w0 = (slot & 15) << 3;
    int gr = r0 - 1 + s;
    int g = c / 3;
    const unsigned short* ip = xn + (size_t)z * CDIM * HW + (size_t)g * HW;
    const float* wp = w9 + c * 9;
    float acc[8];
#pragma unroll
    for (int j = 0; j < 8; ++j) acc[j] = b1[c];
#pragma unroll
    for (int ky = 0; ky < 3; ++ky) {
        int hy = gr + ky - 1;
        if ((unsigned)hy < 128u)
            dw_row(acc, ip + (hy << 7) + w0, w0,
                   wp[ky * 3 + 0], wp[ky * 3 + 1], wp[ky * 3 + 2]);
    }
    u16x8 o;
#pragma unroll
    for (int j = 0; j < 8; ++j) o[j] = f2bf(acc[j]);
    *(u16x8*)(f1 + (size_t)z * CH3 * NT + (size_t)c * NT + (s << 7) + w0) = o;
}

// ---------------------------------------------------------------------------
// FFN depthwise 3x3 on f2 tile -> f3, vectorized 8 px/thread.
// grid (576, Z), 256 thr = full NF tile per block.
// ---------------------------------------------------------------------------
__global__ __launch_bounds__(256) void dw2_tile(const unsigned short* __restrict__ f2,
                                                const float* __restrict__ w9,
                                                const float* __restrict__ b1,
                                                unsigned short* __restrict__ f3, int r0) {
    int c = blockIdx.x, z = blockIdx.y;
    int slot = threadIdx.x;       // 0..255
    int rr = slot >> 4;           // 0..15
    int w0 = (slot & 15) << 3;
    const unsigned short* ip = f2 + (size_t)z * CH3 * NT + (size_t)c * NT;
    const float* wp = w9 + c * 9;
    float acc[8];
#pragma unroll
    for (int j = 0; j < 8; ++j) acc[j] = b1[c];
#pragma unroll
    for (int ky = 0; ky < 3; ++ky) {
        int gy = r0 + rr + ky - 1;
        if ((unsigned)gy < 128u)
            dw_row(acc, ip + ((rr + ky) << 7) + w0, w0,
                   wp[ky * 3 + 0], wp[ky * 3 + 1], wp[ky * 3 + 2]);
    }
    u16x8 o;
#pragma unroll
    for (int j = 0; j < 8; ++j) o[j] = f2bf(acc[j]);
    *(u16x8*)(f3 + (size_t)z * CH3 * NF + (size_t)c * NF + (rr << 7) + w0) = o;
}

// ---------------------------------------------------------------------------
extern "C" void kernel_launch(void* const* d_in, const int* in_sizes, int n_in,
                              void* d_out, int out_size, void* d_ws, size_t ws_size,
                              hipStream_t stream) {
    const float* x      = (const float*)d_in[0];
    const float* ln1w   = (const float*)d_in[1];
    const float* ln1b   = (const float*)d_in[2];
    const float* qkv_w  = (const float*)d_in[3];
    const float* qkv_b  = (const float*)d_in[4];
    const float* qdw_w  = (const float*)d_in[5];
    const float* qdw_b  = (const float*)d_in[6];
    const float* temp   = (const float*)d_in[7];
    const float* prompt = (const float*)d_in[8];
    const float* proj_w = (const float*)d_in[9];
    const float* proj_b = (const float*)d_in[10];
    const float* ln2w   = (const float*)d_in[11];
    const float* ln2b   = (const float*)d_in[12];
    const float* dw1_w  = (const float*)d_in[13];
    const float* dw1_b  = (const float*)d_in[14];
    const float* pm_w   = (const float*)d_in[15];
    const float* pm_b   = (const float*)d_in[16];
    const float* dw2_w  = (const float*)d_in[17];
    const float* dw2_b  = (const float*)d_in[18];
    const float* po_w   = (const float*)d_in[19];
    const float* po_b   = (const float*)d_in[20];
    float* out = (float*)d_out;   // x2 lives here between proj and po
    (void)in_sizes; (void)n_in; (void)out_size;

    // ---- pick phase-1 group size PG and FFN group size NG to fit ws_size ----
    auto al = [](size_t b) { return (b + 255) & ~(size_t)255; };
    auto need = [&](int PG, int NG) -> size_t {
        size_t rA = al((size_t)PG * CH3 * HW * 2);
        size_t rB_attn = (size_t)PG * CH3 * HW * 2;
        size_t rB_ffn = (size_t)NG * CDIM * HW * 2 + (size_t)NG * CH3 * NT * 2;
        size_t rB = al(rB_attn > rB_ffn ? rB_attn : rB_ffn);
        return rA + rB + al((size_t)PG * NHEADS * NSL * 2304 * 4) +
               al((size_t)PG * NHEADS * 2304 * 4) + al((size_t)PG * 384 * 4) + 4096;
    };
    int PG = 8, NG = 4;
    if (need(PG, NG) > ws_size) { PG = 2; NG = 4; }
    if (need(PG, NG) > ws_size) { PG = 1; NG = 2; }

    // ---- arena ----
    size_t off = 0;
    char* base = (char*)d_ws;
    auto alloc = [&](size_t bytes) -> char* {
        char* p = base + off;
        off = (off + bytes + 255) & ~(size_t)255;
        return p;
    };
    size_t rB_attn = (size_t)PG * CH3 * HW * 2;
    size_t rB_ffn  = (size_t)NG * CDIM * HW * 2 + (size_t)NG * CH3 * NT * 2;
    unsigned short* regionA = (unsigned short*)alloc((size_t)PG * CH3 * HW * 2);
    unsigned short* regionB = (unsigned short*)alloc(rB_attn > rB_ffn ? rB_attn : rB_ffn);
    float* G0p  = (float*)alloc((size_t)PG * NHEADS * NSL * 2304 * 4);
    float* Amat = (float*)alloc((size_t)PG * NHEADS * 2304 * 4);
    float* invn = (float*)alloc((size_t)PG * 384 * 4);

    unsigned short* preQKV  = regionA;                 // [z][576][HW] bf16
    unsigned short* attnout = regionA;                 // [z][192][HW] bf16 (preQKV dead)
    unsigned short* f1      = regionA;                 // [z][576][NT] bf16 (FFN)
    unsigned short* f3      = regionA;                 // aliases f1
    unsigned short* xnA     = regionB;                 // [z][192][HW] bf16 (attn LN)
    unsigned short* qkvT    = regionB;                 // [z][576][HW] bf16 (xn dead)
    unsigned short* xnF     = regionB;                 // [z][192][HW] bf16 (FFN LN)
    unsigned short* f2      = regionB + (size_t)NG * CDIM * HW;  // [z][576][NT] bf16

    dim3 blk(256);

    // ---------------- phase 1+2: attention, PG batches at a time ----------------
    for (int b0 = 0; b0 < NB; b0 += PG) {
        const float* xb = x + (size_t)b0 * CDIM * HW;
        float* x2b      = out + (size_t)b0 * CDIM * HW;

        // LN1 -> xnA bf16
        ln_norm<<<dim3(64, PG), blk, 0, stream>>>(xb, ln1w, ln1b, xnA);

        // qkv 1x1 -> preQKV bf16   [grid 128x9xPG]
        gemm_mfma<0><<<dim3(HW / 128, CH3 / 64, PG), blk, 0, stream>>>(
            qkv_w, xnA, HW, (long)CDIM * HW, qkv_b,
            nullptr, 0, 0, preQKV, HW, (long)CH3 * HW, CH3, CDIM);

        // depthwise 3x3 + prompt -> qkvT bf16 (overwrites xnA, already consumed)
        dwp<<<dim3(8, CH3, PG), blk, 0, stream>>>(preQKV, qdw_w, qdw_b, prompt, qkvT);

        inv_norms1<<<dim3(384, PG), blk, 0, stream>>>(qkvT, invn);
        gram1<<<dim3(NSL, NHEADS, PG), blk, 0, stream>>>(qkvT, G0p);
        softmax1<<<dim3(NHEADS, PG), blk, 0, stream>>>(G0p, invn, temp, Amat);
        apply1<<<dim3(64, NHEADS, PG), blk, 0, stream>>>(qkvT, Amat, attnout);

        // proj 1x1 + residual(x) -> x2 (fp32, in d_out)   [grid 128x3xPG]
        gemm_mfma<2><<<dim3(HW / 128, CDIM / 64, PG), blk, 0, stream>>>(
            proj_w, attnout, HW, (long)CDIM * HW, proj_b,
            xb, HW, (long)CDIM * HW, x2b, HW, (long)CDIM * HW, CDIM, CDIM);
    }

    // ---------------- phase 3+4: FFN, groups of NG batches ----------------
    for (int g0 = 0; g0 < NB; g0 += NG) {
        float* x2g = out + (size_t)g0 * CDIM * HW;

        // LN2 -> xnF bf16
        ln_norm<<<dim3(64, NG), blk, 0, stream>>>(x2g, ln2w, ln2b, xnF);

        for (int t = 0; t < 128 / TROWS; ++t) {
            int r0 = t * TROWS;
            dw1_tile<<<dim3(648, NG), blk, 0, stream>>>(
                xnF, dw1_w, dw1_b, f1, r0);
            // pm 576->576 + gelu -> f2 bf16   [grid 18x9xNG]
            gemm_mfma<1><<<dim3(NT / 128, CH3 / 64, NG), blk, 0, stream>>>(
                pm_w, f1, NT, (long)CH3 * NT, pm_b,
                nullptr, 0, 0, f2, NT, (long)CH3 * NT, CH3, CH3);
            dw2_tile<<<dim3(CH3, NG), blk, 0, stream>>>(
                f2, dw2_w, dw2_b, f3, r0);
            // po 576->192 + residual(x2 rows) -> out rows  [grid 16x3xNG]
            gemm_mfma<2><<<dim3(NF / 128, CDIM / 64, NG), blk, 0, stream>>>(
                po_w, f3, NF, (long)CH3 * NF, po_b,
                x2g + (size_t)r0 * 128, HW, (long)CDIM * HW,
                x2g + (size_t)r0 * 128, HW, (long)CDIM * HW, CDIM, CH3);
        }
    }
}

// Round 4
// 1695.008 us; speedup vs baseline: 2.5931x; 1.3161x over previous
//
#include <hip/hip_runtime.h>

// Problem constants
#define HW     16384      // 128*128
#define NB     8
#define CDIM   192
#define CH3    576
#define NHEADS 4
#define CHH    48
#define TROWS  16           // FFN tile rows
#define TSLOT  18           // + halo
#define NT     (TSLOT*128)  // 2304
#define NF     (TROWS*128)  // 2048
#define LDA    40           // LDS k-stride (bf16 elems)
#define NSL    64           // gram1 n-slices

typedef short  v8s  __attribute__((ext_vector_type(8)));
typedef float  v4f  __attribute__((ext_vector_type(4)));
typedef unsigned short u16x8 __attribute__((ext_vector_type(8)));

__device__ __forceinline__ float bf2f(unsigned short s) {
    return __uint_as_float(((unsigned)s) << 16);
}
__device__ __forceinline__ unsigned short f2bf(float f) {
    unsigned u = __float_as_uint(f);
    return (unsigned short)((u + 0x7fffu + ((u >> 16) & 1u)) >> 16);
}
__device__ __forceinline__ float gelu_f(float x) {
    return 0.5f * x * (1.0f + erff(x * 0.70710678118654752f));
}

// Vectorized 3x3 row update: acc[0..7] += taps of row [w0-1, w0+8]
__device__ __forceinline__ void dw_row(float acc[8], const unsigned short* __restrict__ row,
                                       int w0, float wl, float wc, float wr) {
    u16x8 m = *(const u16x8*)row;
    float mv[8];
#pragma unroll
    for (int j = 0; j < 8; ++j) mv[j] = bf2f(m[j]);
    float lft = (w0 > 0)   ? bf2f(row[-1]) : 0.f;
    float rgt = (w0 < 120) ? bf2f(row[8])  : 0.f;
    acc[0] = fmaf(wl, lft, acc[0]);
#pragma unroll
    for (int j = 1; j < 8; ++j) acc[j] = fmaf(wl, mv[j - 1], acc[j]);
#pragma unroll
    for (int j = 0; j < 8; ++j) acc[j] = fmaf(wc, mv[j], acc[j]);
#pragma unroll
    for (int j = 0; j < 7; ++j) acc[j] = fmaf(wr, mv[j + 1], acc[j]);
    acc[7] = fmaf(wr, rgt, acc[7]);
}

// ---------------------------------------------------------------------------
// Convert 4 fp32 weight matrices to a packed bf16 arena. grid (162, 4)
// ---------------------------------------------------------------------------
__global__ __launch_bounds__(256) void wcvt(const float* __restrict__ s0,
                                            const float* __restrict__ s1,
                                            const float* __restrict__ s2,
                                            const float* __restrict__ s3,
                                            unsigned short* __restrict__ d,
                                            int n0, int n1, int n2, int n3) {
    const float* srcs[4] = {s0, s1, s2, s3};
    int cnts[4] = {n0, n1, n2, n3};
    int offs[4] = {0, n0, n0 + n1, n0 + n1 + n2};
    int w = blockIdx.y;
    const float* s = srcs[w];
    unsigned short* o = d + offs[w];
    int i = (blockIdx.x * 256 + threadIdx.x) * 8;
    if (i + 8 <= cnts[w]) {
        float4 a = *(const float4*)(s + i);
        float4 b = *(const float4*)(s + i + 4);
        u16x8 u;
        u[0] = f2bf(a.x); u[1] = f2bf(a.y); u[2] = f2bf(a.z); u[3] = f2bf(a.w);
        u[4] = f2bf(b.x); u[5] = f2bf(b.y); u[6] = f2bf(b.z); u[7] = f2bf(b.w);
        *(u16x8*)(o + i) = u;
    } else {
        for (int j = i; j < cnts[w]; ++j) o[j] = f2bf(s[j]);
    }
}

// ---------------------------------------------------------------------------
// LayerNorm -> normalized bf16 tensor xn[z][c][p]. grid (64, Z)
// ---------------------------------------------------------------------------
__global__ __launch_bounds__(256) void ln_norm(const float* __restrict__ x,
                                               const float* __restrict__ lnw,
                                               const float* __restrict__ lnb,
                                               unsigned short* __restrict__ xn) {
    int p = blockIdx.x * 256 + threadIdx.x;
    int z = blockIdx.y;
    const float* xp = x + (size_t)z * CDIM * HW;
    unsigned short* op = xn + (size_t)z * CDIM * HW;
    float s = 0.f, ss = 0.f;
    for (int c = 0; c < CDIM; ++c) {
        float v = xp[(size_t)c * HW + p];
        s += v; ss += v * v;
    }
    float m = s * (1.0f / CDIM);
    float var = ss * (1.0f / CDIM) - m * m;
    float r = 1.0f / sqrtf(var + 1e-5f);
    for (int c = 0; c < CDIM; ++c) {
        float v = (xp[(size_t)c * HW + p] - m) * r * lnw[c] + lnb[c];
        op[(size_t)c * HW + p] = f2bf(v);
    }
}

// ---------------------------------------------------------------------------
// MFMA bf16 GEMM: out[m,n] = sum_k W[m,k] * X[k,n]  (fp32 acc/epilogue)
// W is pre-converted bf16; A-fragments load DIRECT from global (L2-resident).
// B staged to LDS [n][k] with XOR swizzle: elem (n,k) at n*LDA + (k^((n>>4&3)<<3))
//   -> write conflicts 16-way -> 4-way; read side XOR uniform per instruction.
// Block: 256 thr = 4 waves (2x2), tile M=64 x N=128, K-step 32.
// EPI 0: +bias -> bf16; 1: +bias,gelu -> bf16; 2: +bias,+res(fp32) -> fp32.
// grid (N/128, M/64, Z)
// ---------------------------------------------------------------------------
template <int EPI>
__global__ __launch_bounds__(256) void gemm_mfma(
    const unsigned short* __restrict__ Awb,
    const unsigned short* __restrict__ Bin, int b_cs, long b_zs,
    const float* __restrict__ bias,
    const float* __restrict__ res, int r_cs, long r_zs,
    void* __restrict__ outp, int o_cs, long o_zs,
    int M, int K) {
    __shared__ unsigned short Blbs[128 * LDA];

    const int t  = threadIdx.x;
    const int n0 = blockIdx.x * 128;
    const int m0 = blockIdx.y * 64;
    const int z  = blockIdx.z;

    const int wid = t >> 6, lane = t & 63;
    const int lm = lane & 15, quad = lane >> 4;
    const int wm = (wid & 1) * 32, wn = (wid >> 1) * 64;

    v4f acc[2][4];
#pragma unroll
    for (int mi = 0; mi < 2; ++mi)
#pragma unroll
        for (int ni = 0; ni < 4; ++ni) acc[mi][ni] = (v4f)0.0f;

    // B staging coords: 32 k x 8 n-chunks of 16
    const int bk = t >> 3, nc = (t & 7) << 4;
    const int xw = ((nc >> 4) & 3) << 3;        // write-side XOR (same for rows nc..nc+15)

    // A fragment row pointers (bf16 weights, k-contiguous)
    const unsigned short* ar0 = Awb + (size_t)(m0 + wm + lm) * K + quad * 8;
    const unsigned short* ar1 = Awb + (size_t)(m0 + wm + 16 + lm) * K + quad * 8;

    for (int k0 = 0; k0 < K; k0 += 32) {
        if (k0) __syncthreads();
        // --- stage B (32 k x 128 n) transposed to [n][k^swz] ---
        {
            const unsigned short* bp = Bin + (size_t)z * b_zs +
                                       (size_t)(k0 + bk) * b_cs + n0 + nc;
            u16x8 u0 = *(const u16x8*)bp;
            u16x8 u1 = *(const u16x8*)(bp + 8);
            int kk = bk ^ xw;
#pragma unroll
            for (int i = 0; i < 8; ++i) {
                Blbs[(nc + i) * LDA + kk]     = u0[i];
                Blbs[(nc + 8 + i) * LDA + kk] = u1[i];
            }
        }
        // --- A fragments direct from global (issue before barrier) ---
        v8s a0 = *(const v8s*)(ar0 + k0);
        v8s a1 = *(const v8s*)(ar1 + k0);
        __syncthreads();
        // --- 2x4 MFMA 16x16x32 ---
        v8s b[4];
#pragma unroll
        for (int ni = 0; ni < 4; ++ni) {
            int rn = wn + ni * 16 + lm;
            int xr = ((rn >> 4) & 3) << 3;      // uniform across lm
            b[ni] = *(const v8s*)&Blbs[rn * LDA + ((quad * 8) ^ xr)];
        }
#pragma unroll
        for (int ni = 0; ni < 4; ++ni) {
            acc[0][ni] = __builtin_amdgcn_mfma_f32_16x16x32_bf16(a0, b[ni], acc[0][ni], 0, 0, 0);
            acc[1][ni] = __builtin_amdgcn_mfma_f32_16x16x32_bf16(a1, b[ni], acc[1][ni], 0, 0, 0);
        }
    }

    // --- epilogue: D row = quad*4+r, col = lm ---
#pragma unroll
    for (int mi = 0; mi < 2; ++mi)
#pragma unroll
        for (int ni = 0; ni < 4; ++ni)
#pragma unroll
            for (int r = 0; r < 4; ++r) {
                int gm = m0 + wm + mi * 16 + quad * 4 + r;
                int gn = n0 + wn + ni * 16 + lm;
                float v = acc[mi][ni][r] + bias[gm];
                if (EPI == 1) v = gelu_f(v);
                if (EPI == 2) {
                    size_t ri = (size_t)z * r_zs + (size_t)gm * r_cs + gn;
                    size_t oi = (size_t)z * o_zs + (size_t)gm * o_cs + gn;
                    ((float*)outp)[oi] = v + res[ri];
                } else {
                    size_t oi = (size_t)z * o_zs + (size_t)gm * o_cs + gn;
                    ((unsigned short*)outp)[oi] = f2bf(v);
                }
            }
}

// ---------------------------------------------------------------------------
// Depthwise 3x3 (pad=1) + bias + prompt[c%192], vectorized 8 px/thread.
// grid (8, 576, Z)
// ---------------------------------------------------------------------------
__global__ __launch_bounds__(256) void dwp(const unsigned short* __restrict__ in,
                                           const float* __restrict__ w9,
                                           const float* __restrict__ b1,
                                           const float* __restrict__ prompt,
                                           unsigned short* __restrict__ out) {
    int slot = blockIdx.x * 256 + threadIdx.x;   // 0..2047
    int c = blockIdx.y;
    int z = blockIdx.z;
    int h = slot >> 4;            // row 0..127
    int w0 = (slot & 15) << 3;    // col base (mult of 8)
    const unsigned short* ip = in + (size_t)z * CH3 * HW + (size_t)c * HW;
    const float* wp = w9 + c * 9;
    float base = b1[c] + prompt[c % CDIM];
    float acc[8];
#pragma unroll
    for (int j = 0; j < 8; ++j) acc[j] = base;
#pragma unroll
    for (int ky = 0; ky < 3; ++ky) {
        int hy = h + ky - 1;
        if ((unsigned)hy < 128u)
            dw_row(acc, ip + (hy << 7) + w0, w0,
                   wp[ky * 3 + 0], wp[ky * 3 + 1], wp[ky * 3 + 2]);
    }
    u16x8 o;
#pragma unroll
    for (int j = 0; j < 8; ++j) o[j] = f2bf(acc[j]);
    *(u16x8*)(out + (size_t)z * CH3 * HW + (size_t)c * HW + (h << 7) + w0) = o;
}

// ---------------------------------------------------------------------------
// 1/max(L2norm,1e-12) per q,k channel (0..383). grid (384, Z)
// ---------------------------------------------------------------------------
__global__ __launch_bounds__(256) void inv_norms1(const unsigned short* __restrict__ qk,
                                                  float* __restrict__ invn) {
    int ch = blockIdx.x;
    int z = blockIdx.y;
    const unsigned short* p = qk + (size_t)z * CH3 * HW + (size_t)ch * HW;
    float ss = 0.f;
    for (int i = threadIdx.x; i < HW; i += 256) { float v = bf2f(p[i]); ss += v * v; }
    __shared__ float r[256];
    r[threadIdx.x] = ss;
    __syncthreads();
    for (int off = 128; off; off >>= 1) {
        if (threadIdx.x < (unsigned)off) r[threadIdx.x] += r[threadIdx.x + off];
        __syncthreads();
    }
    if (threadIdx.x == 0) invn[z * 384 + ch] = 1.0f / fmaxf(sqrtf(r[0]), 1e-12f);
}

// ---------------------------------------------------------------------------
// Gram partials via MFMA: G0p[((z*4+h)*NSL + sl)][qc*48+kc].
// grid (NSL, 4 heads, Z), 256 thr = 4 waves.
// ---------------------------------------------------------------------------
__global__ __launch_bounds__(256) void gram1(const unsigned short* __restrict__ qk,
                                             float* __restrict__ G0p) {
    const int sl = blockIdx.x, h = blockIdx.y, z = blockIdx.z;
    const int t = threadIdx.x;
    const int wid = t >> 6, lane = t & 63;
    const int lm = lane & 15, quad = lane >> 4;

    const unsigned short* qb = qk + (size_t)z * CH3 * HW + (size_t)(h * CHH) * HW;
    const unsigned short* kb = qk + (size_t)z * CH3 * HW + (size_t)(192 + h * CHH) * HW;

    v4f acc[3][3];
#pragma unroll
    for (int mi = 0; mi < 3; ++mi)
#pragma unroll
        for (int ni = 0; ni < 3; ++ni) acc[mi][ni] = (v4f)0.0f;

    // wave covers n in [sl*256 + wid*64, +64): two K-steps of 32
    const int nbase = sl * 256 + wid * 64 + quad * 8;
#pragma unroll
    for (int ks = 0; ks < 2; ++ks) {
        const int n = nbase + ks * 32;
        v8s a[3], b[3];
#pragma unroll
        for (int i = 0; i < 3; ++i) {
            a[i] = *(const v8s*)(qb + (size_t)(i * 16 + lm) * HW + n);
            b[i] = *(const v8s*)(kb + (size_t)(i * 16 + lm) * HW + n);
        }
#pragma unroll
        for (int mi = 0; mi < 3; ++mi)
#pragma unroll
            for (int ni = 0; ni < 3; ++ni)
                acc[mi][ni] = __builtin_amdgcn_mfma_f32_16x16x32_bf16(
                    a[mi], b[ni], acc[mi][ni], 0, 0, 0);
    }

    // cross-wave reduce in LDS, one fp32 partial per block
    __shared__ float Gs[4][2304];
#pragma unroll
    for (int mi = 0; mi < 3; ++mi)
#pragma unroll
        for (int ni = 0; ni < 3; ++ni)
#pragma unroll
            for (int r = 0; r < 4; ++r)
                Gs[wid][(mi * 16 + quad * 4 + r) * 48 + ni * 16 + lm] = acc[mi][ni][r];
    __syncthreads();
    float* gp = G0p + (((size_t)z * NHEADS + h) * NSL + sl) * 2304;
    for (int i = t; i < 2304; i += 256)
        gp[i] = Gs[0][i] + Gs[1][i] + Gs[2][i] + Gs[3][i];
}

// ---------------------------------------------------------------------------
// logits = T*G*invq*invk; softmax over d. grid (4, Z) x 256 thr, NSL partials
// ---------------------------------------------------------------------------
__global__ __launch_bounds__(256) void softmax1(const float* __restrict__ G0p,
                                                const float* __restrict__ invn,
                                                const float* __restrict__ temp,
                                                float* __restrict__ Amat) {
    int h = blockIdx.x;
    int z = blockIdx.y;
    int t = threadIdx.x;
    __shared__ float Gs[2304];
    const float* gbase = G0p + ((size_t)z * NHEADS + h) * NSL * 2304;
    for (int i = t; i < 2304; i += 256) {
        float s = 0.f;
#pragma unroll 8
        for (int sl = 0; sl < NSL; ++sl) s += gbase[(size_t)sl * 2304 + i];
        Gs[i] = s;
    }
    __syncthreads();
    if (t < 48) {
        float T = temp[h];
        const float* iv = invn + (size_t)z * 384;
        float invq = iv[h * CHH + t];
        const float* gr = &Gs[t * 48];
        float lg[48];
        float mx = -1e30f;
#pragma unroll
        for (int d = 0; d < 48; ++d) {
            float l = T * gr[d] * invq * iv[192 + h * CHH + d];
            lg[d] = l;
            mx = fmaxf(mx, l);
        }
        float sum = 0.f;
#pragma unroll
        for (int d = 0; d < 48; ++d) { float e = expf(lg[d] - mx); lg[d] = e; sum += e; }
        float inv = 1.0f / sum;
        float* ap = Amat + ((size_t)z * NHEADS + h) * 2304 + t * 48;
#pragma unroll
        for (int d = 0; d < 48; ++d) ap[d] = lg[d] * inv;
    }
}

// ---------------------------------------------------------------------------
// attnout[c,n] = sum_d A[c,d]*v~[d,n] per head (bf16 in/out). grid (64, 4, Z)
// ---------------------------------------------------------------------------
__global__ __launch_bounds__(256) void apply1(const unsigned short* __restrict__ qkvT,
                                              const float* __restrict__ Amat,
                                              unsigned short* __restrict__ attnout) {
    int n = blockIdx.x * 256 + threadIdx.x;
    int h = blockIdx.y;
    int z = blockIdx.z;
    __shared__ float As[2304];
    for (int i = threadIdx.x; i < 2304; i += 256)
        As[i] = Amat[((size_t)z * NHEADS + h) * 2304 + i];
    __syncthreads();
    const unsigned short* vp = qkvT + (size_t)z * CH3 * HW + (size_t)(384 + h * CHH) * HW + n;
    float acc[48];
#pragma unroll
    for (int c = 0; c < 48; ++c) acc[c] = 0.f;
    for (int d = 0; d < 48; ++d) {
        float v = bf2f(vp[(size_t)d * HW]);
#pragma unroll
        for (int c = 0; c < 48; ++c) acc[c] = fmaf(As[c * 48 + d], v, acc[c]);
    }
    unsigned short* op = attnout + (size_t)z * CDIM * HW + (size_t)(h * CHH) * HW + n;
#pragma unroll
    for (int c = 0; c < 48; ++c) op[(size_t)c * HW] = f2bf(acc[c]);
}

// ---------------------------------------------------------------------------
// FFN grouped 3x3 (192->576) on pre-normalized bf16 xn, row-tile +halo,
// vectorized 8 px/thread. grid (648, Z): idx -> c (0..575), slot (0..287).
// ---------------------------------------------------------------------------
__global__ __launch_bounds__(256) void dw1_tile(const unsigned short* __restrict__ xn,
                                                const float* __restrict__ w9,
                                                const float* __restrict__ b1,
                                                unsigned short* __restrict__ f1, int r0) {
    int idx = blockIdx.x * 256 + threadIdx.x;   // 0..165887
    int z = blockIdx.y;
    int c = idx / 288;
    int slot = idx - c * 288;
    int s = slot >> 4;            // tile row 0..17
    int w0 = (slot & 15) << 3;
    int gr = r0 - 1 + s;
    int g = c / 3;
    const unsigned short* ip = xn + (size_t)z * CDIM * HW + (size_t)g * HW;
    const float* wp = w9 + c * 9;
    float acc[8];
#pragma unroll
    for (int j = 0; j < 8; ++j) acc[j] = b1[c];
#pragma unroll
    for (int ky = 0; ky < 3; ++ky) {
        int hy = gr + ky - 1;
        if ((unsigned)hy < 128u)
            dw_row(acc, ip + (hy << 7) + w0, w0,
                   wp[ky * 3 + 0], wp[ky * 3 + 1], wp[ky * 3 + 2]);
    }
    u16x8 o;
#pragma unroll
    for (int j = 0; j < 8; ++j) o[j] = f2bf(acc[j]);
    *(u16x8*)(f1 + (size_t)z * CH3 * NT + (size_t)c * NT + (s << 7) + w0) = o;
}

// ---------------------------------------------------------------------------
// FFN depthwise 3x3 on f2 tile -> f3, vectorized 8 px/thread.
// grid (576, Z), 256 thr = full NF tile per block.
// ---------------------------------------------------------------------------
__global__ __launch_bounds__(256) void dw2_tile(const unsigned short* __restrict__ f2,
                                                const float* __restrict__ w9,
                                                const float* __restrict__ b1,
                                                unsigned short* __restrict__ f3, int r0) {
    int c = blockIdx.x, z = blockIdx.y;
    int slot = threadIdx.x;       // 0..255
    int rr = slot >> 4;           // 0..15
    int w0 = (slot & 15) << 3;
    const unsigned short* ip = f2 + (size_t)z * CH3 * NT + (size_t)c * NT;
    const float* wp = w9 + c * 9;
    float acc[8];
#pragma unroll
    for (int j = 0; j < 8; ++j) acc[j] = b1[c];
#pragma unroll
    for (int ky = 0; ky < 3; ++ky) {
        int gy = r0 + rr + ky - 1;
        if ((unsigned)gy < 128u)
            dw_row(acc, ip + ((rr + ky) << 7) + w0, w0,
                   wp[ky * 3 + 0], wp[ky * 3 + 1], wp[ky * 3 + 2]);
    }
    u16x8 o;
#pragma unroll
    for (int j = 0; j < 8; ++j) o[j] = f2bf(acc[j]);
    *(u16x8*)(f3 + (size_t)z * CH3 * NF + (size_t)c * NF + (rr << 7) + w0) = o;
}

// ---------------------------------------------------------------------------
extern "C" void kernel_launch(void* const* d_in, const int* in_sizes, int n_in,
                              void* d_out, int out_size, void* d_ws, size_t ws_size,
                              hipStream_t stream) {
    const float* x      = (const float*)d_in[0];
    const float* ln1w   = (const float*)d_in[1];
    const float* ln1b   = (const float*)d_in[2];
    const float* qkv_w  = (const float*)d_in[3];
    const float* qkv_b  = (const float*)d_in[4];
    const float* qdw_w  = (const float*)d_in[5];
    const float* qdw_b  = (const float*)d_in[6];
    const float* temp   = (const float*)d_in[7];
    const float* prompt = (const float*)d_in[8];
    const float* proj_w = (const float*)d_in[9];
    const float* proj_b = (const float*)d_in[10];
    const float* ln2w   = (const float*)d_in[11];
    const float* ln2b   = (const float*)d_in[12];
    const float* dw1_w  = (const float*)d_in[13];
    const float* dw1_b  = (const float*)d_in[14];
    const float* pm_w   = (const float*)d_in[15];
    const float* pm_b   = (const float*)d_in[16];
    const float* dw2_w  = (const float*)d_in[17];
    const float* dw2_b  = (const float*)d_in[18];
    const float* po_w   = (const float*)d_in[19];
    const float* po_b   = (const float*)d_in[20];
    float* out = (float*)d_out;   // x2 lives here between proj and po
    (void)in_sizes; (void)n_in; (void)out_size;

    // bf16 weight arena element counts/offsets
    const int NWQ = CH3 * CDIM;          // 110592
    const int NWP = CDIM * CDIM;         // 36864
    const int NWM = CH3 * CH3;           // 331776
    const int NWO = CDIM * CH3;          // 110592
    const int NWALL = NWQ + NWP + NWM + NWO;

    // ---- pick phase-1 group size PG and FFN group size NG to fit ws_size ----
    auto al = [](size_t b) { return (b + 255) & ~(size_t)255; };
    auto need = [&](int PG, int NG) -> size_t {
        size_t rA = al((size_t)PG * CH3 * HW * 2);
        size_t rB_attn = (size_t)PG * CH3 * HW * 2;
        size_t rB_ffn = (size_t)NG * CDIM * HW * 2 + (size_t)NG * CH3 * NT * 2;
        size_t rB = al(rB_attn > rB_ffn ? rB_attn : rB_ffn);
        return rA + rB + al((size_t)PG * NHEADS * NSL * 2304 * 4) +
               al((size_t)PG * NHEADS * 2304 * 4) + al((size_t)PG * 384 * 4) +
               al((size_t)NWALL * 2) + 4096;
    };
    int PG = 8, NG = 4;
    if (need(PG, NG) > ws_size) { PG = 2; NG = 4; }
    if (need(PG, NG) > ws_size) { PG = 1; NG = 2; }

    // ---- arena ----
    size_t off = 0;
    char* base = (char*)d_ws;
    auto alloc = [&](size_t bytes) -> char* {
        char* p = base + off;
        off = (off + bytes + 255) & ~(size_t)255;
        return p;
    };
    size_t rB_attn = (size_t)PG * CH3 * HW * 2;
    size_t rB_ffn  = (size_t)NG * CDIM * HW * 2 + (size_t)NG * CH3 * NT * 2;
    unsigned short* regionA = (unsigned short*)alloc((size_t)PG * CH3 * HW * 2);
    unsigned short* regionB = (unsigned short*)alloc(rB_attn > rB_ffn ? rB_attn : rB_ffn);
    float* G0p  = (float*)alloc((size_t)PG * NHEADS * NSL * 2304 * 4);
    float* Amat = (float*)alloc((size_t)PG * NHEADS * 2304 * 4);
    float* invn = (float*)alloc((size_t)PG * 384 * 4);
    unsigned short* wbf = (unsigned short*)alloc((size_t)NWALL * 2);

    unsigned short* wq  = wbf;
    unsigned short* wpj = wbf + NWQ;
    unsigned short* wpm = wbf + NWQ + NWP;
    unsigned short* wpo = wbf + NWQ + NWP + NWM;

    unsigned short* preQKV  = regionA;                 // [z][576][HW] bf16
    unsigned short* attnout = regionA;                 // [z][192][HW] bf16 (preQKV dead)
    unsigned short* f1      = regionA;                 // [z][576][NT] bf16 (FFN)
    unsigned short* f3      = regionA;                 // aliases f1
    unsigned short* xnA     = regionB;                 // [z][192][HW] bf16 (attn LN)
    unsigned short* qkvT    = regionB;                 // [z][576][HW] bf16 (xn dead)
    unsigned short* xnF     = regionB;                 // [z][192][HW] bf16 (FFN LN)
    unsigned short* f2      = regionB + (size_t)NG * CDIM * HW;  // [z][576][NT] bf16

    dim3 blk(256);

    // ---- weights fp32 -> bf16, once ----
    wcvt<<<dim3((NWM + 2047) / 2048, 4), blk, 0, stream>>>(
        qkv_w, proj_w, pm_w, po_w, wbf, NWQ, NWP, NWM, NWO);

    // ---------------- phase 1+2: attention, PG batches at a time ----------------
    for (int b0 = 0; b0 < NB; b0 += PG) {
        const float* xb = x + (size_t)b0 * CDIM * HW;
        float* x2b      = out + (size_t)b0 * CDIM * HW;

        // LN1 -> xnA bf16
        ln_norm<<<dim3(64, PG), blk, 0, stream>>>(xb, ln1w, ln1b, xnA);

        // qkv 1x1 -> preQKV bf16   [grid 128x9xPG]
        gemm_mfma<0><<<dim3(HW / 128, CH3 / 64, PG), blk, 0, stream>>>(
            wq, xnA, HW, (long)CDIM * HW, qkv_b,
            nullptr, 0, 0, preQKV, HW, (long)CH3 * HW, CH3, CDIM);

        // depthwise 3x3 + prompt -> qkvT bf16 (overwrites xnA, already consumed)
        dwp<<<dim3(8, CH3, PG), blk, 0, stream>>>(preQKV, qdw_w, qdw_b, prompt, qkvT);

        inv_norms1<<<dim3(384, PG), blk, 0, stream>>>(qkvT, invn);
        gram1<<<dim3(NSL, NHEADS, PG), blk, 0, stream>>>(qkvT, G0p);
        softmax1<<<dim3(NHEADS, PG), blk, 0, stream>>>(G0p, invn, temp, Amat);
        apply1<<<dim3(64, NHEADS, PG), blk, 0, stream>>>(qkvT, Amat, attnout);

        // proj 1x1 + residual(x) -> x2 (fp32, in d_out)   [grid 128x3xPG]
        gemm_mfma<2><<<dim3(HW / 128, CDIM / 64, PG), blk, 0, stream>>>(
            wpj, attnout, HW, (long)CDIM * HW, proj_b,
            xb, HW, (long)CDIM * HW, x2b, HW, (long)CDIM * HW, CDIM, CDIM);
    }

    // ---------------- phase 3+4: FFN, groups of NG batches ----------------
    for (int g0 = 0; g0 < NB; g0 += NG) {
        float* x2g = out + (size_t)g0 * CDIM * HW;

        // LN2 -> xnF bf16
        ln_norm<<<dim3(64, NG), blk, 0, stream>>>(x2g, ln2w, ln2b, xnF);

        for (int t = 0; t < 128 / TROWS; ++t) {
            int r0 = t * TROWS;
            dw1_tile<<<dim3(648, NG), blk, 0, stream>>>(
                xnF, dw1_w, dw1_b, f1, r0);
            // pm 576->576 + gelu -> f2 bf16   [grid 18x9xNG]
            gemm_mfma<1><<<dim3(NT / 128, CH3 / 64, NG), blk, 0, stream>>>(
                wpm, f1, NT, (long)CH3 * NT, pm_b,
                nullptr, 0, 0, f2, NT, (long)CH3 * NT, CH3, CH3);
            dw2_tile<<<dim3(CH3, NG), blk, 0, stream>>>(
                f2, dw2_w, dw2_b, f3, r0);
            // po 576->192 + residual(x2 rows) -> out rows  [grid 16x3xNG]
            gemm_mfma<2><<<dim3(NF / 128, CDIM / 64, NG), blk, 0, stream>>>(
                wpo, f3, NF, (long)CH3 * NF, po_b,
                x2g + (size_t)r0 * 128, HW, (long)CDIM * HW,
                x2g + (size_t)r0 * 128, HW, (long)CDIM * HW, CDIM, CH3);
        }
    }
}